// Round 9
// baseline (243.649 us; speedup 1.0000x reference)
//
#include <hip/hip_runtime.h>
#include <hip/hip_bf16.h>
#include <math.h>

// ---------------------------------------------------------------------------
// DogeCDMoE round 9: EXACT round-8 file (passed, 238.9us) with ONE delta:
// experts_kernel restructured to async LDS staging via global_load_lds
// (VGPR-free load path; compiler cannot serialize it into registers, which
// killed the R4/R8 register-prefetch attempts). Per-wave private LDS slice +
// per-wave s_waitcnt vmcnt(0) drain -- no cross-wave barriers in the loop.
// Math is bit-identical to R8 (same chunks, same butterfly, same sum order).
// ---------------------------------------------------------------------------

#define TOKENS 2048
#define DIM    1024
#define INTER  2048
#define NKEYS  128
#define TOPK   8
#define HEADS  4
#define NINF  -3.4e38f

typedef unsigned short ushort_t;
typedef __attribute__((ext_vector_type(8))) short bf16x8;
typedef __attribute__((ext_vector_type(4))) float f32x4;

__device__ __forceinline__ float bf2f(ushort_t u) {
    unsigned int x = (unsigned int)u << 16;
    float f; __builtin_memcpy(&f, &x, 4); return f;
}
__device__ __forceinline__ ushort_t f2bf_rne(float f) {
    unsigned int x; __builtin_memcpy(&x, &f, 4);
    x += 0x7fffu + ((x >> 16) & 1u);
    return (ushort_t)(x >> 16);
}
__device__ __forceinline__ void gload_lds16(const void* g, void* l) {
    __builtin_amdgcn_global_load_lds(
        (const __attribute__((address_space(1))) unsigned int*)g,
        (__attribute__((address_space(3))) unsigned int*)l, 16, 0, 0);
}

// ---------------- fused f32 -> bf16 (RNE) for all 5 tensors -----------------
__global__ __launch_bounds__(256) void convert_all(
    const float* __restrict__ h,  const float* __restrict__ wq,
    const float* __restrict__ wg, const float* __restrict__ wu,
    const float* __restrict__ wd,
    ushort_t* __restrict__ hb,  ushort_t* __restrict__ wqb,
    ushort_t* __restrict__ wgb, ushort_t* __restrict__ wub,
    ushort_t* __restrict__ wdb) {
    const int i = blockIdx.x * 256 + threadIdx.x;
    const float* src; ushort_t* dst; int off;
    if      (i <  262144) { src = h;  dst = hb;  off = i; }
    else if (i <  294912) { src = wq; dst = wqb; off = i - 262144; }
    else if (i <  557056) { src = wg; dst = wgb; off = i - 294912; }
    else if (i <  819200) { src = wu; dst = wub; off = i - 557056; }
    else                  { src = wd; dst = wdb; off = i - 819200; }
    const float4* p = (const float4*)src + (size_t)off * 2;
    const float4 a = p[0], b = p[1];
    uint4 o;
    o.x = (unsigned)f2bf_rne(a.x) | ((unsigned)f2bf_rne(a.y) << 16);
    o.y = (unsigned)f2bf_rne(a.z) | ((unsigned)f2bf_rne(a.w) << 16);
    o.z = (unsigned)f2bf_rne(b.x) | ((unsigned)f2bf_rne(b.y) << 16);
    o.w = (unsigned)f2bf_rne(b.z) | ((unsigned)f2bf_rne(b.w) << 16);
    ((uint4*)dst)[off] = o;
}

// ---------------- bf16 MFMA GEMM: C[M,N] = A[M,K] @ B[N,K]^T ----------------
// EPI 0: f32 = acc | 1: bf16 = silu(extra_bf16)*acc | 2: f32 = acc+extra_f32
// EPI 3: bf16 = acc
template<int BM, int BN, int WR, int WC, int FM, int FN, int EPI>
__global__ __launch_bounds__(256) void mfma_gemm(const ushort_t* __restrict__ A,
                                                 const ushort_t* __restrict__ B,
                                                 const void* __restrict__ extra,
                                                 void* __restrict__ Cout,
                                                 int M, int N, int K) {
    static_assert(WR * WC == 4 && WR * FM * 16 == BM && WC * FN * 16 == BN, "geom");
    __shared__ ushort_t As[BM * 32];
    __shared__ ushort_t Bs[BN * 32];
    const int tid = threadIdx.x;
    const int w = tid >> 6, lane = tid & 63;
    const int wr = w / WC, wc = w % WC;
    const int m0 = blockIdx.y * BM, n0 = blockIdx.x * BN;

    const int srow = (w << 4) + (lane >> 2);
    const int scol = (lane & 3) << 3;
    const ushort_t* Ag = &A[(size_t)(m0 + srow) * K + scol];
    const ushort_t* Bg = &B[(size_t)(n0 + srow) * K + scol];
    ushort_t* Al = &As[w << 9];
    ushort_t* Bl = &Bs[w << 9];

    const int frow = lane & 15;
    const int fcol = (lane >> 4) << 3;
    const ushort_t* Afr = &As[(size_t)(wr * FM * 16 + frow) * 32 + fcol];
    const ushort_t* Bfr = &Bs[(size_t)(wc * FN * 16 + frow) * 32 + fcol];

    f32x4 acc[FM][FN];
#pragma unroll
    for (int i = 0; i < FM; ++i)
#pragma unroll
        for (int j = 0; j < FN; ++j) acc[i][j] = (f32x4){0.f, 0.f, 0.f, 0.f};

    for (int k0 = 0; k0 < K; k0 += 32) {
        __syncthreads();
#pragma unroll
        for (int i = 0; i < BM / 64; ++i)
            gload_lds16(Ag + (size_t)i * 64 * K + k0, Al + i * 2048);
#pragma unroll
        for (int i = 0; i < BN / 64; ++i)
            gload_lds16(Bg + (size_t)i * 64 * K + k0, Bl + i * 2048);
        __syncthreads();

        bf16x8 af[FM], bfv[FN];
#pragma unroll
        for (int i = 0; i < FM; ++i) af[i] = *(const bf16x8*)(Afr + i * 512);
#pragma unroll
        for (int j = 0; j < FN; ++j) bfv[j] = *(const bf16x8*)(Bfr + j * 512);
#pragma unroll
        for (int i = 0; i < FM; ++i)
#pragma unroll
            for (int j = 0; j < FN; ++j)
                acc[i][j] = __builtin_amdgcn_mfma_f32_16x16x32_bf16(
                    af[i], bfv[j], acc[i][j], 0, 0, 0);
    }

    const int crow0 = m0 + wr * FM * 16 + ((lane >> 4) << 2);
    const int ccol0 = n0 + wc * FN * 16 + (lane & 15);
#pragma unroll
    for (int i = 0; i < FM; ++i)
#pragma unroll
        for (int j = 0; j < FN; ++j)
#pragma unroll
            for (int r = 0; r < 4; ++r) {
                const size_t off = (size_t)(crow0 + i * 16 + r) * N + ccol0 + j * 16;
                float v = acc[i][j][r];
                if (EPI == 1) {
                    const float gg = bf2f(((const ushort_t*)extra)[off]);
                    v *= gg / (1.f + __expf(-gg));
                    ((ushort_t*)Cout)[off] = f2bf_rne(v);
                } else if (EPI == 2) {
                    ((float*)Cout)[off] = v + ((const float*)extra)[off];
                } else if (EPI == 3) {
                    ((ushort_t*)Cout)[off] = f2bf_rne(v);
                } else {
                    ((float*)Cout)[off] = v;
                }
            }
}

// ---------------- wave-parallel product-key routing (unchanged) --------------
__global__ __launch_bounds__(256) void topk_kernel(const float* __restrict__ q,
                                                   const float* __restrict__ keys,
                                                   int* __restrict__ eidx,
                                                   float* __restrict__ ewgt) {
    const int t = blockIdx.x;
    const int head = threadIdx.x >> 6;
    const int lane = threadIdx.x & 63;

    const float4* qx = (const float4*)&q[(size_t)t * 256 + head * 32];
    const float4* qy = (const float4*)&q[(size_t)t * 256 + 128 + head * 32];
    float4 qxv[8], qyv[8];
#pragma unroll
    for (int n = 0; n < 8; ++n) { qxv[n] = qx[n]; qyv[n] = qy[n]; }

    float cx0, cx1, cy0, cy1;
    {
        float s[4];
#pragma unroll
        for (int j = 0; j < 2; ++j) {
            const int k = 2 * lane + j;
            const float4* kx = (const float4*)&keys[(size_t)(((head << 7) | k) * 2 + 0) * 32];
            const float4* ky = (const float4*)&keys[(size_t)(((head << 7) | k) * 2 + 1) * 32];
            float sx = 0.f, sy = 0.f;
#pragma unroll
            for (int n = 0; n < 8; ++n) {
                const float4 a = qxv[n], b = kx[n];
                sx += a.x * b.x + a.y * b.y + a.z * b.z + a.w * b.w;
                const float4 c = qyv[n], d = ky[n];
                sy += c.x * d.x + c.y * d.y + c.z * d.z + c.w * d.w;
            }
            s[j * 2] = sx; s[j * 2 + 1] = sy;
        }
        cx0 = s[0]; cy0 = s[1]; cx1 = s[2]; cy1 = s[3];
    }

    float sx_mine = NINF, sy_mine = NINF;
    int sxi_mine = 0, syi_mine = 0;
    {
        float c0 = cx0, c1 = cx1;
#pragma unroll
        for (int it = 0; it < TOPK; ++it) {
            float bv; int bi;
            if (c1 > c0) { bv = c1; bi = 2 * lane + 1; } else { bv = c0; bi = 2 * lane; }
#pragma unroll
            for (int m = 1; m < 64; m <<= 1) {
                const float ov = __shfl_xor(bv, m);
                const int   oi = __shfl_xor(bi, m);
                if (ov > bv || (ov == bv && oi < bi)) { bv = ov; bi = oi; }
            }
            if (lane == it) { sx_mine = bv; sxi_mine = bi; }
            if (bi == 2 * lane) c0 = NINF;
            else if (bi == 2 * lane + 1) c1 = NINF;
        }
    }
    {
        float c0 = cy0, c1 = cy1;
#pragma unroll
        for (int it = 0; it < TOPK; ++it) {
            float bv; int bi;
            if (c1 > c0) { bv = c1; bi = 2 * lane + 1; } else { bv = c0; bi = 2 * lane; }
#pragma unroll
            for (int m = 1; m < 64; m <<= 1) {
                const float ov = __shfl_xor(bv, m);
                const int   oi = __shfl_xor(bi, m);
                if (ov > bv || (ov == bv && oi < bi)) { bv = ov; bi = oi; }
            }
            if (lane == it) { sy_mine = bv; syi_mine = bi; }
            if (bi == 2 * lane) c0 = NINF;
            else if (bi == 2 * lane + 1) c1 = NINF;
        }
    }

    const float sa = __shfl(sx_mine, lane >> 3);
    const int   ia = __shfl(sxi_mine, lane >> 3);
    const float sb = __shfl(sy_mine, lane & 7);
    const int   ib = __shfl(syi_mine, lane & 7);
    float cv = sa + sb;
    const int ci = ia * NKEYS + ib;

    float fs_mine = NINF; int fi_mine = 0;
#pragma unroll
    for (int it = 0; it < TOPK; ++it) {
        float bv = cv; int bp = lane; int bx = ci;
#pragma unroll
        for (int m = 1; m < 64; m <<= 1) {
            const float ov = __shfl_xor(bv, m);
            const int   op = __shfl_xor(bp, m);
            const int   ox = __shfl_xor(bx, m);
            if (ov > bv || (ov == bv && op < bp)) { bv = ov; bp = op; bx = ox; }
        }
        if (lane == it) { fs_mine = bv; fi_mine = bx; }
        if (lane == bp) cv = NINF;
    }

    float f[8];
#pragma unroll
    for (int j = 0; j < 8; ++j) f[j] = __shfl(fs_mine, j);
    float mx = f[0];
#pragma unroll
    for (int j = 1; j < 8; ++j) mx = fmaxf(mx, f[j]);
    float ssum = 0.f;
#pragma unroll
    for (int j = 0; j < 8; ++j) ssum += expf(f[j] - mx);
    if (lane < 8) {
        eidx[t * 32 + head * 8 + lane] = fi_mine;
        ewgt[t * 32 + head * 8 + lane] = expf(fs_mine - mx) / ssum;
    }
}

// ---------------- experts: async-LDS-staged gather [THE DELTA] ---------------
// One block per token, 4 waves. Wave w owns experts w*8..w*8+7, processed one
// per batch: stage de+ue rows (8 KB) into the wave's PRIVATE LDS slice via
// global_load_lds (no VGPR cost, 8 x 1KB in flight), per-wave vmcnt(0) drain,
// then dot/silu/accumulate from LDS. No cross-wave barriers inside the loop.
// Per-lane chunk order, butterfly reduce, and final sum order are bit-identical
// to the R4/R8 kernel.
__global__ __launch_bounds__(256) void experts_kernel(const float* __restrict__ hs,
                                                      const float* __restrict__ down_embed,
                                                      const float* __restrict__ up_embed,
                                                      const int* __restrict__ eidx,
                                                      const float* __restrict__ ewgt,
                                                      float* __restrict__ estate) {
    __shared__ float sbuf[4][2][1024];   // 32 KB: [wave][de|ue][dim]; aliased
                                         // as partial[4][256] float4 at the end
    __shared__ int   eid[32];
    __shared__ float wl[32];
    const int t = blockIdx.x;
    const int tid = threadIdx.x;
    const int w = tid >> 6, lane = tid & 63;

    if (tid < 32) { eid[tid] = eidx[t * 32 + tid]; wl[tid] = ewgt[t * 32 + tid]; }

    const float4* hs4 = (const float4*)hs + (size_t)t * 256;
    float4 h[4];
#pragma unroll
    for (int i = 0; i < 4; ++i) h[i] = hs4[i * 64 + lane];

    float4 acc[4];
#pragma unroll
    for (int i = 0; i < 4; ++i) acc[i] = (float4){0.f, 0.f, 0.f, 0.f};

    float* dd = &sbuf[w][0][0];
    float* ud = &sbuf[w][1][0];
    const float4* d4 = (const float4*)dd;
    const float4* u4 = (const float4*)ud;
    __syncthreads();   // eid/wl visible

    for (int b = 0; b < 8; ++b) {
        const int slot = w * 8 + b;               // wave-uniform
        const int e = eid[slot];
        const float* ds = down_embed + (size_t)e * 1024;
        const float* us = up_embed   + (size_t)e * 1024;
        // stage 8 KB: LDS dest wave-uniform, HW appends lane*16B; src per-lane
#pragma unroll
        for (int c2 = 0; c2 < 4; ++c2) {
            gload_lds16(ds + c2 * 256 + lane * 4, dd + c2 * 256);
            gload_lds16(us + c2 * 256 + lane * 4, ud + c2 * 256);
        }
        asm volatile("s_waitcnt vmcnt(0)" ::: "memory");   // per-wave drain

        float s = 0.f;
#pragma unroll
        for (int i = 0; i < 4; ++i) {
            const float4 d = d4[i * 64 + lane];
            s += h[i].x * d.x + h[i].y * d.y + h[i].z * d.z + h[i].w * d.w;
        }
#pragma unroll
        for (int m = 1; m < 64; m <<= 1) s += __shfl_xor(s, m);
        const float c = (s / (1.f + __expf(-s))) * wl[slot];
#pragma unroll
        for (int i = 0; i < 4; ++i) {
            const float4 u = u4[i * 64 + lane];
            acc[i].x += c * u.x; acc[i].y += c * u.y;
            acc[i].z += c * u.z; acc[i].w += c * u.w;
        }
        // next stage overwrites only THIS wave's slice; reads above complete
        // before the next gload_lds issues (lgkm waits inserted by compiler)
    }

    // final cross-wave reduce: alias sbuf as partial[4][256] float4
    __syncthreads();   // everyone done with their slice
    float4* part = (float4*)sbuf;
#pragma unroll
    for (int i = 0; i < 4; ++i) part[w * 256 + i * 64 + lane] = acc[i];
    __syncthreads();

    const float4 p0 = part[tid], p1 = part[256 + tid];
    const float4 p2 = part[512 + tid], p3 = part[768 + tid];
    float4 o;
    o.x = p0.x + p1.x + p2.x + p3.x;
    o.y = p0.y + p1.y + p2.y + p3.y;
    o.z = p0.z + p1.z + p2.z + p3.z;
    o.w = p0.w + p1.w + p2.w + p3.w;
    ((float4*)estate)[(size_t)t * 256 + tid] = o;
}

// ---------------------------------------------------------------------------
extern "C" void kernel_launch(void* const* d_in, const int* in_sizes, int n_in,
                              void* d_out, int out_size, void* d_ws, size_t ws_size,
                              hipStream_t stream) {
    (void)in_sizes; (void)n_in; (void)out_size; (void)ws_size;
    const float* hidden = (const float*)d_in[0];
    const float* wq     = (const float*)d_in[1];
    const float* keys   = (const float*)d_in[2];
    const float* down_e = (const float*)d_in[3];
    const float* up_e   = (const float*)d_in[4];
    const float* wgate  = (const float*)d_in[5];
    const float* wup    = (const float*)d_in[6];
    const float* wdown  = (const float*)d_in[7];
    float* out = (float*)d_out;
    char* ws = (char*)d_ws;

    // workspace layout: EXACT round-4/7/8 (passed). estate(f32,8MB) aliases
    // g(bf16,8MB): g dead after up-GEMM reads it; experts writes after.
    ushort_t* hb  = (ushort_t*)(ws);                     // 4 MB
    ushort_t* wqb = (ushort_t*)(ws + (4u << 20));        // 0.5 MB
    ushort_t* wgb = (ushort_t*)(ws + (4608u << 10));     // 4 MB
    ushort_t* wub = (ushort_t*)(ws + (8704u << 10));     // 4 MB
    ushort_t* wdb = (ushort_t*)(ws + (12800u << 10));    // 4 MB
    float*    q   = (float*)   (ws + (16896u << 10));    // 2 MB
    ushort_t* act = (ushort_t*)(ws + (18944u << 10));    // 8 MB
    ushort_t* g   = (ushort_t*)(ws + (27136u << 10));    // 8 MB
    float* estate = (float*)g;                           // alias
    float*    wgt = (float*)   (ws + (35328u << 10));    // 0.25 MB
    int*     eidx = (int*)     (ws + (35584u << 10));    // 0.25 MB

    convert_all<<<4224, 256, 0, stream>>>(hidden, wq, wgate, wup, wdown,
                                          hb, wqb, wgb, wub, wdb);

    // 1) q = hidden @ wq^T  (2048 x 256 x 1024), f32 out for routing
    mfma_gemm<64, 64, 2, 2, 2, 2, 0><<<dim3(4, 32), 256, 0, stream>>>(
        hb, wqb, nullptr, q, TOKENS, 256, DIM);
    // 2) routing (wave-parallel)
    topk_kernel<<<TOKENS, 256, 0, stream>>>(q, keys, eidx, wgt);
    // 3) g = hidden @ wgate^T -> bf16
    mfma_gemm<64, 128, 1, 4, 4, 2, 3><<<dim3(16, 32), 256, 0, stream>>>(
        hb, wgb, nullptr, g, TOKENS, INTER, DIM);
    // 4) act = silu(g) * (hidden @ wup^T) -> bf16
    mfma_gemm<64, 128, 1, 4, 4, 2, 1><<<dim3(16, 32), 256, 0, stream>>>(
        hb, wub, g, act, TOKENS, INTER, DIM);
    // 5) experts (writes estate over dead g)
    experts_kernel<<<TOKENS, 256, 0, stream>>>(hidden, down_e, up_e, eidx, wgt, estate);
    // 6) out = act @ wdown^T + estate  (2048 x 1024 x 2048)
    mfma_gemm<64, 128, 1, 4, 4, 2, 2><<<dim3(8, 32), 256, 0, stream>>>(
        act, wdb, estate, out, TOKENS, DIM, INTER);
}

// Round 10
// 228.436 us; speedup vs baseline: 1.0666x; 1.0666x over previous
//
#include <hip/hip_runtime.h>
#include <hip/hip_bf16.h>
#include <math.h>

// ---------------------------------------------------------------------------
// DogeCDMoE round 10: EXACT round-9 launches except ONE structural delta:
// the gate GEMM and the experts gather are GRID-FUSED into one kernel
// (512 GEMM blocks interleaved 1:4 with 2048 expert blocks). The gather is
// HBM-latency-bound (3.1 TB/s, MFMA idle); the gate GEMM is MFMA-bound (HBM
// idle) -- co-resident waves overlap the two (m114). estate is written to
// d_out (full coverage) and the down-GEMM adds in-place (same-thread
// read-then-write per element), so the workspace layout is exactly R9's
// proven one with the g/estate alias REMOVED (safer than R9).
// Experts body = exact R8 version; GEMM body = exact R7/R9 <64,128,1,4,4,2>.
// ---------------------------------------------------------------------------

#define TOKENS 2048
#define DIM    1024
#define INTER  2048
#define NKEYS  128
#define TOPK   8
#define HEADS  4
#define NINF  -3.4e38f

typedef unsigned short ushort_t;
typedef __attribute__((ext_vector_type(8))) short bf16x8;
typedef __attribute__((ext_vector_type(4))) float f32x4;

__device__ __forceinline__ float bf2f(ushort_t u) {
    unsigned int x = (unsigned int)u << 16;
    float f; __builtin_memcpy(&f, &x, 4); return f;
}
__device__ __forceinline__ ushort_t f2bf_rne(float f) {
    unsigned int x; __builtin_memcpy(&x, &f, 4);
    x += 0x7fffu + ((x >> 16) & 1u);
    return (ushort_t)(x >> 16);
}
__device__ __forceinline__ void gload_lds16(const void* g, void* l) {
    __builtin_amdgcn_global_load_lds(
        (const __attribute__((address_space(1))) unsigned int*)g,
        (__attribute__((address_space(3))) unsigned int*)l, 16, 0, 0);
}

// ---------------- fused f32 -> bf16 (RNE) for all 5 tensors -----------------
__global__ __launch_bounds__(256) void convert_all(
    const float* __restrict__ h,  const float* __restrict__ wq,
    const float* __restrict__ wg, const float* __restrict__ wu,
    const float* __restrict__ wd,
    ushort_t* __restrict__ hb,  ushort_t* __restrict__ wqb,
    ushort_t* __restrict__ wgb, ushort_t* __restrict__ wub,
    ushort_t* __restrict__ wdb) {
    const int i = blockIdx.x * 256 + threadIdx.x;
    const float* src; ushort_t* dst; int off;
    if      (i <  262144) { src = h;  dst = hb;  off = i; }
    else if (i <  294912) { src = wq; dst = wqb; off = i - 262144; }
    else if (i <  557056) { src = wg; dst = wgb; off = i - 294912; }
    else if (i <  819200) { src = wu; dst = wub; off = i - 557056; }
    else                  { src = wd; dst = wdb; off = i - 819200; }
    const float4* p = (const float4*)src + (size_t)off * 2;
    const float4 a = p[0], b = p[1];
    uint4 o;
    o.x = (unsigned)f2bf_rne(a.x) | ((unsigned)f2bf_rne(a.y) << 16);
    o.y = (unsigned)f2bf_rne(a.z) | ((unsigned)f2bf_rne(a.w) << 16);
    o.z = (unsigned)f2bf_rne(b.x) | ((unsigned)f2bf_rne(b.y) << 16);
    o.w = (unsigned)f2bf_rne(b.z) | ((unsigned)f2bf_rne(b.w) << 16);
    ((uint4*)dst)[off] = o;
}

// ---------------- bf16 MFMA GEMM: C[M,N] = A[M,K] @ B[N,K]^T ----------------
// EPI 0: f32 = acc | 1: bf16 = silu(extra_bf16)*acc | 2: f32 = acc+extra_f32
// EPI 3: bf16 = acc   (EPI 2 may have Cout == extra: same-thread in-place add)
template<int BM, int BN, int WR, int WC, int FM, int FN, int EPI>
__global__ __launch_bounds__(256) void mfma_gemm(const ushort_t* __restrict__ A,
                                                 const ushort_t* __restrict__ B,
                                                 const void* __restrict__ extra,
                                                 void* __restrict__ Cout,
                                                 int M, int N, int K) {
    static_assert(WR * WC == 4 && WR * FM * 16 == BM && WC * FN * 16 == BN, "geom");
    __shared__ ushort_t As[BM * 32];
    __shared__ ushort_t Bs[BN * 32];
    const int tid = threadIdx.x;
    const int w = tid >> 6, lane = tid & 63;
    const int wr = w / WC, wc = w % WC;
    const int m0 = blockIdx.y * BM, n0 = blockIdx.x * BN;

    const int srow = (w << 4) + (lane >> 2);
    const int scol = (lane & 3) << 3;
    const ushort_t* Ag = &A[(size_t)(m0 + srow) * K + scol];
    const ushort_t* Bg = &B[(size_t)(n0 + srow) * K + scol];
    ushort_t* Al = &As[w << 9];
    ushort_t* Bl = &Bs[w << 9];

    const int frow = lane & 15;
    const int fcol = (lane >> 4) << 3;
    const ushort_t* Afr = &As[(size_t)(wr * FM * 16 + frow) * 32 + fcol];
    const ushort_t* Bfr = &Bs[(size_t)(wc * FN * 16 + frow) * 32 + fcol];

    f32x4 acc[FM][FN];
#pragma unroll
    for (int i = 0; i < FM; ++i)
#pragma unroll
        for (int j = 0; j < FN; ++j) acc[i][j] = (f32x4){0.f, 0.f, 0.f, 0.f};

    for (int k0 = 0; k0 < K; k0 += 32) {
        __syncthreads();
#pragma unroll
        for (int i = 0; i < BM / 64; ++i)
            gload_lds16(Ag + (size_t)i * 64 * K + k0, Al + i * 2048);
#pragma unroll
        for (int i = 0; i < BN / 64; ++i)
            gload_lds16(Bg + (size_t)i * 64 * K + k0, Bl + i * 2048);
        __syncthreads();

        bf16x8 af[FM], bfv[FN];
#pragma unroll
        for (int i = 0; i < FM; ++i) af[i] = *(const bf16x8*)(Afr + i * 512);
#pragma unroll
        for (int j = 0; j < FN; ++j) bfv[j] = *(const bf16x8*)(Bfr + j * 512);
#pragma unroll
        for (int i = 0; i < FM; ++i)
#pragma unroll
            for (int j = 0; j < FN; ++j)
                acc[i][j] = __builtin_amdgcn_mfma_f32_16x16x32_bf16(
                    af[i], bfv[j], acc[i][j], 0, 0, 0);
    }

    const int crow0 = m0 + wr * FM * 16 + ((lane >> 4) << 2);
    const int ccol0 = n0 + wc * FN * 16 + (lane & 15);
#pragma unroll
    for (int i = 0; i < FM; ++i)
#pragma unroll
        for (int j = 0; j < FN; ++j)
#pragma unroll
            for (int r = 0; r < 4; ++r) {
                const size_t off = (size_t)(crow0 + i * 16 + r) * N + ccol0 + j * 16;
                float v = acc[i][j][r];
                if (EPI == 1) {
                    const float gg = bf2f(((const ushort_t*)extra)[off]);
                    v *= gg / (1.f + __expf(-gg));
                    ((ushort_t*)Cout)[off] = f2bf_rne(v);
                } else if (EPI == 2) {
                    ((float*)Cout)[off] = v + ((const float*)extra)[off];
                } else if (EPI == 3) {
                    ((ushort_t*)Cout)[off] = f2bf_rne(v);
                } else {
                    ((float*)Cout)[off] = v;
                }
            }
}

// ---------------- wave-parallel product-key routing (unchanged) --------------
__global__ __launch_bounds__(256) void topk_kernel(const float* __restrict__ q,
                                                   const float* __restrict__ keys,
                                                   int* __restrict__ eidx,
                                                   float* __restrict__ ewgt) {
    const int t = blockIdx.x;
    const int head = threadIdx.x >> 6;
    const int lane = threadIdx.x & 63;

    const float4* qx = (const float4*)&q[(size_t)t * 256 + head * 32];
    const float4* qy = (const float4*)&q[(size_t)t * 256 + 128 + head * 32];
    float4 qxv[8], qyv[8];
#pragma unroll
    for (int n = 0; n < 8; ++n) { qxv[n] = qx[n]; qyv[n] = qy[n]; }

    float cx0, cx1, cy0, cy1;
    {
        float s[4];
#pragma unroll
        for (int j = 0; j < 2; ++j) {
            const int k = 2 * lane + j;
            const float4* kx = (const float4*)&keys[(size_t)(((head << 7) | k) * 2 + 0) * 32];
            const float4* ky = (const float4*)&keys[(size_t)(((head << 7) | k) * 2 + 1) * 32];
            float sx = 0.f, sy = 0.f;
#pragma unroll
            for (int n = 0; n < 8; ++n) {
                const float4 a = qxv[n], b = kx[n];
                sx += a.x * b.x + a.y * b.y + a.z * b.z + a.w * b.w;
                const float4 c = qyv[n], d = ky[n];
                sy += c.x * d.x + c.y * d.y + c.z * d.z + c.w * d.w;
            }
            s[j * 2] = sx; s[j * 2 + 1] = sy;
        }
        cx0 = s[0]; cy0 = s[1]; cx1 = s[2]; cy1 = s[3];
    }

    float sx_mine = NINF, sy_mine = NINF;
    int sxi_mine = 0, syi_mine = 0;
    {
        float c0 = cx0, c1 = cx1;
#pragma unroll
        for (int it = 0; it < TOPK; ++it) {
            float bv; int bi;
            if (c1 > c0) { bv = c1; bi = 2 * lane + 1; } else { bv = c0; bi = 2 * lane; }
#pragma unroll
            for (int m = 1; m < 64; m <<= 1) {
                const float ov = __shfl_xor(bv, m);
                const int   oi = __shfl_xor(bi, m);
                if (ov > bv || (ov == bv && oi < bi)) { bv = ov; bi = oi; }
            }
            if (lane == it) { sx_mine = bv; sxi_mine = bi; }
            if (bi == 2 * lane) c0 = NINF;
            else if (bi == 2 * lane + 1) c1 = NINF;
        }
    }
    {
        float c0 = cy0, c1 = cy1;
#pragma unroll
        for (int it = 0; it < TOPK; ++it) {
            float bv; int bi;
            if (c1 > c0) { bv = c1; bi = 2 * lane + 1; } else { bv = c0; bi = 2 * lane; }
#pragma unroll
            for (int m = 1; m < 64; m <<= 1) {
                const float ov = __shfl_xor(bv, m);
                const int   oi = __shfl_xor(bi, m);
                if (ov > bv || (ov == bv && oi < bi)) { bv = ov; bi = oi; }
            }
            if (lane == it) { sy_mine = bv; syi_mine = bi; }
            if (bi == 2 * lane) c0 = NINF;
            else if (bi == 2 * lane + 1) c1 = NINF;
        }
    }

    const float sa = __shfl(sx_mine, lane >> 3);
    const int   ia = __shfl(sxi_mine, lane >> 3);
    const float sb = __shfl(sy_mine, lane & 7);
    const int   ib = __shfl(syi_mine, lane & 7);
    float cv = sa + sb;
    const int ci = ia * NKEYS + ib;

    float fs_mine = NINF; int fi_mine = 0;
#pragma unroll
    for (int it = 0; it < TOPK; ++it) {
        float bv = cv; int bp = lane; int bx = ci;
#pragma unroll
        for (int m = 1; m < 64; m <<= 1) {
            const float ov = __shfl_xor(bv, m);
            const int   op = __shfl_xor(bp, m);
            const int   ox = __shfl_xor(bx, m);
            if (ov > bv || (ov == bv && op < bp)) { bv = ov; bp = op; bx = ox; }
        }
        if (lane == it) { fs_mine = bv; fi_mine = bx; }
        if (lane == bp) cv = NINF;
    }

    float f[8];
#pragma unroll
    for (int j = 0; j < 8; ++j) f[j] = __shfl(fs_mine, j);
    float mx = f[0];
#pragma unroll
    for (int j = 1; j < 8; ++j) mx = fmaxf(mx, f[j]);
    float ssum = 0.f;
#pragma unroll
    for (int j = 0; j < 8; ++j) ssum += expf(f[j] - mx);
    if (lane < 8) {
        eidx[t * 32 + head * 8 + lane] = fi_mine;
        ewgt[t * 32 + head * 8 + lane] = expf(fs_mine - mx) / ssum;
    }
}

// ---------------- FUSED: gate GEMM blocks + experts blocks [THE DELTA] ------
// 2560 blocks: b%5==4 -> gate-GEMM block id (b-4)/5 of 512 (64x128 tile,
// bx=id&15, by=id>>4, EPI3 -> g bf16). Otherwise expert block for token
// t = b - (b+1)/5 (exact R8 experts body; estate -> OUT f32, full coverage).
// Shared 16.9KB LDS arena (max of the two paths). Branch is block-uniform.
__global__ __launch_bounds__(256) void gate_experts_kernel(
    const ushort_t* __restrict__ A,  const ushort_t* __restrict__ B,
    ushort_t* __restrict__ G,
    const float* __restrict__ hs, const float* __restrict__ down_embed,
    const float* __restrict__ up_embed, const int* __restrict__ eidx,
    const float* __restrict__ ewgt, float* __restrict__ estate) {
    __shared__ __align__(16) char smem[16896];
    const int b = blockIdx.x;
    const int tid = threadIdx.x;
    const int w = tid >> 6, lane = tid & 63;

    if (b % 5 == 4) {
        // ---------------- gate GEMM path: BM=64 BN=128 WR=1 WC=4 FM=4 FN=2 --
        const int id = (b - 4) / 5;
        const int m0 = (id >> 4) * 64, n0 = (id & 15) * 128;
        const int N = INTER, K = DIM;
        ushort_t* As = (ushort_t*)smem;             // 64*32*2  = 4 KB
        ushort_t* Bs = (ushort_t*)(smem + 4096);    // 128*32*2 = 8 KB
        const int wc = w;                            // WR=1 -> wr=0
        const int srow = (w << 4) + (lane >> 2);
        const int scol = (lane & 3) << 3;
        const ushort_t* Ag = &A[(size_t)(m0 + srow) * K + scol];
        const ushort_t* Bg = &B[(size_t)(n0 + srow) * K + scol];
        ushort_t* Al = &As[w << 9];
        ushort_t* Bl = &Bs[w << 9];
        const int frow = lane & 15;
        const int fcol = (lane >> 4) << 3;
        const ushort_t* Afr = &As[(size_t)frow * 32 + fcol];
        const ushort_t* Bfr = &Bs[(size_t)(wc * 32 + frow) * 32 + fcol];

        f32x4 acc[4][2];
#pragma unroll
        for (int i = 0; i < 4; ++i)
#pragma unroll
            for (int j = 0; j < 2; ++j) acc[i][j] = (f32x4){0.f, 0.f, 0.f, 0.f};

        for (int k0 = 0; k0 < K; k0 += 32) {
            __syncthreads();
            gload_lds16(Ag + k0, Al);
#pragma unroll
            for (int i = 0; i < 2; ++i)
                gload_lds16(Bg + (size_t)i * 64 * K + k0, Bl + i * 2048);
            __syncthreads();

            bf16x8 af[4], bfv[2];
#pragma unroll
            for (int i = 0; i < 4; ++i) af[i] = *(const bf16x8*)(Afr + i * 512);
#pragma unroll
            for (int j = 0; j < 2; ++j) bfv[j] = *(const bf16x8*)(Bfr + j * 512);
#pragma unroll
            for (int i = 0; i < 4; ++i)
#pragma unroll
                for (int j = 0; j < 2; ++j)
                    acc[i][j] = __builtin_amdgcn_mfma_f32_16x16x32_bf16(
                        af[i], bfv[j], acc[i][j], 0, 0, 0);
        }

        const int crow0 = m0 + ((lane >> 4) << 2);
        const int ccol0 = n0 + wc * 32 + (lane & 15);
#pragma unroll
        for (int i = 0; i < 4; ++i)
#pragma unroll
            for (int j = 0; j < 2; ++j)
#pragma unroll
                for (int r = 0; r < 4; ++r) {
                    const size_t off = (size_t)(crow0 + i * 16 + r) * N + ccol0 + j * 16;
                    G[off] = f2bf_rne(acc[i][j][r]);
                }
    } else {
        // ---------------- experts path: exact R8 body, estate -> OUT --------
        const int t = b - (b + 1) / 5;
        float4 (*partial)[256] = (float4(*)[256])smem;      // 16 KB
        int*   eid = (int*)(smem + 16384);                  // 128 B
        float* wl  = (float*)(smem + 16512);                // 128 B

        if (tid < 32) { eid[tid] = eidx[t * 32 + tid]; wl[tid] = ewgt[t * 32 + tid]; }

        const float4* hs4 = (const float4*)hs + (size_t)t * 256;
        float4 h[4];
#pragma unroll
        for (int i = 0; i < 4; ++i) h[i] = hs4[i * 64 + lane];

        const float4* de4 = (const float4*)down_embed;
        const float4* ue4 = (const float4*)up_embed;
        __syncthreads();

        float4 acc[4];
#pragma unroll
        for (int i = 0; i < 4; ++i) acc[i] = (float4){0.f, 0.f, 0.f, 0.f};

        float4 d[4], u[4], nd[4], nu[4];
        {
            const size_t bb = (size_t)eid[w * 8] * 256;
#pragma unroll
            for (int i = 0; i < 4; ++i) { d[i] = de4[bb + i * 64 + lane]; u[i] = ue4[bb + i * 64 + lane]; }
        }
#pragma unroll
        for (int jj = 0; jj < 8; ++jj) {
            if (jj < 7) {
                const size_t bb = (size_t)eid[w * 8 + jj + 1] * 256;
#pragma unroll
                for (int i = 0; i < 4; ++i) { nd[i] = de4[bb + i * 64 + lane]; nu[i] = ue4[bb + i * 64 + lane]; }
            }
            float s = 0.f;
#pragma unroll
            for (int i = 0; i < 4; ++i)
                s += h[i].x * d[i].x + h[i].y * d[i].y + h[i].z * d[i].z + h[i].w * d[i].w;
#pragma unroll
            for (int m = 1; m < 64; m <<= 1) s += __shfl_xor(s, m);
            const float c = (s / (1.f + __expf(-s))) * wl[w * 8 + jj];
#pragma unroll
            for (int i = 0; i < 4; ++i) {
                acc[i].x += c * u[i].x; acc[i].y += c * u[i].y;
                acc[i].z += c * u[i].z; acc[i].w += c * u[i].w;
            }
            if (jj < 7) {
#pragma unroll
                for (int i = 0; i < 4; ++i) { d[i] = nd[i]; u[i] = nu[i]; }
            }
        }

#pragma unroll
        for (int i = 0; i < 4; ++i) partial[w][i * 64 + lane] = acc[i];
        __syncthreads();

        const float4 p0 = partial[0][tid], p1 = partial[1][tid];
        const float4 p2 = partial[2][tid], p3 = partial[3][tid];
        float4 o;
        o.x = p0.x + p1.x + p2.x + p3.x;
        o.y = p0.y + p1.y + p2.y + p3.y;
        o.z = p0.z + p1.z + p2.z + p3.z;
        o.w = p0.w + p1.w + p2.w + p3.w;
        ((float4*)estate)[(size_t)t * 256 + tid] = o;
    }
}

// ---------------------------------------------------------------------------
extern "C" void kernel_launch(void* const* d_in, const int* in_sizes, int n_in,
                              void* d_out, int out_size, void* d_ws, size_t ws_size,
                              hipStream_t stream) {
    (void)in_sizes; (void)n_in; (void)out_size; (void)ws_size;
    const float* hidden = (const float*)d_in[0];
    const float* wq     = (const float*)d_in[1];
    const float* keys   = (const float*)d_in[2];
    const float* down_e = (const float*)d_in[3];
    const float* up_e   = (const float*)d_in[4];
    const float* wgate  = (const float*)d_in[5];
    const float* wup    = (const float*)d_in[6];
    const float* wdown  = (const float*)d_in[7];
    float* out = (float*)d_out;
    char* ws = (char*)d_ws;

    // workspace layout: EXACT round-9 (passed) with the g/estate alias REMOVED
    // (estate now lives in d_out; g region holds only the gate result).
    ushort_t* hb  = (ushort_t*)(ws);                     // 4 MB
    ushort_t* wqb = (ushort_t*)(ws + (4u << 20));        // 0.5 MB
    ushort_t* wgb = (ushort_t*)(ws + (4608u << 10));     // 4 MB
    ushort_t* wub = (ushort_t*)(ws + (8704u << 10));     // 4 MB
    ushort_t* wdb = (ushort_t*)(ws + (12800u << 10));    // 4 MB
    float*    q   = (float*)   (ws + (16896u << 10));    // 2 MB
    ushort_t* act = (ushort_t*)(ws + (18944u << 10));    // 8 MB
    ushort_t* g   = (ushort_t*)(ws + (27136u << 10));    // 8 MB
    float*    wgt = (float*)   (ws + (35328u << 10));    // 0.25 MB
    int*     eidx = (int*)     (ws + (35584u << 10));    // 0.25 MB
    float* estate = out;                                 // 8 MB, in d_out

    convert_all<<<4224, 256, 0, stream>>>(hidden, wq, wgate, wup, wdown,
                                          hb, wqb, wgb, wub, wdb);

    // 1) q = hidden @ wq^T  (2048 x 256 x 1024), f32 out for routing
    mfma_gemm<64, 64, 2, 2, 2, 2, 0><<<dim3(4, 32), 256, 0, stream>>>(
        hb, wqb, nullptr, q, TOKENS, 256, DIM);
    // 2) routing (wave-parallel)
    topk_kernel<<<TOKENS, 256, 0, stream>>>(q, keys, eidx, wgt);
    // 3+5 FUSED) g = hidden @ wgate^T (512 blocks) || experts -> out (2048)
    gate_experts_kernel<<<2560, 256, 0, stream>>>(
        hb, wgb, g, hidden, down_e, up_e, eidx, wgt, estate);
    // 4) act = silu(g) * (hidden @ wup^T) -> bf16
    mfma_gemm<64, 128, 1, 4, 4, 2, 1><<<dim3(16, 32), 256, 0, stream>>>(
        hb, wub, g, act, TOKENS, INTER, DIM);
    // 6) out = act @ wdown^T + out(=estate), in-place same-thread add
    mfma_gemm<64, 128, 1, 4, 4, 2, 2><<<dim3(8, 32), 256, 0, stream>>>(
        act, wdb, estate, out, TOKENS, DIM, INTER);
}

// Round 11
// 218.103 us; speedup vs baseline: 1.1171x; 1.0474x over previous
//
#include <hip/hip_runtime.h>
#include <hip/hip_bf16.h>
#include <math.h>

// ---------------------------------------------------------------------------
// DogeCDMoE round 11: EXACT round-10 file (passed, 228.4us) with ONE delta:
// the up-GEMM joins the fused kernel as a THIRD block type (raw u = h@wup^T,
// same 64x128 geometry as the gate path), and a tiny in-place elementwise
// pass act[i] = silu(g[i]) * u[i] replaces the serial EPI1 up-GEMM.
// 3072 blocks, pattern {E,E,G,E,E,U}. No new aliases; in-place write is
// same-thread elementwise. Experts/gate bodies byte-identical to R10.
// ---------------------------------------------------------------------------

#define TOKENS 2048
#define DIM    1024
#define INTER  2048
#define NKEYS  128
#define TOPK   8
#define HEADS  4
#define NINF  -3.4e38f

typedef unsigned short ushort_t;
typedef __attribute__((ext_vector_type(8))) short bf16x8;
typedef __attribute__((ext_vector_type(4))) float f32x4;

__device__ __forceinline__ float bf2f(ushort_t u) {
    unsigned int x = (unsigned int)u << 16;
    float f; __builtin_memcpy(&f, &x, 4); return f;
}
__device__ __forceinline__ ushort_t f2bf_rne(float f) {
    unsigned int x; __builtin_memcpy(&x, &f, 4);
    x += 0x7fffu + ((x >> 16) & 1u);
    return (ushort_t)(x >> 16);
}
__device__ __forceinline__ void gload_lds16(const void* g, void* l) {
    __builtin_amdgcn_global_load_lds(
        (const __attribute__((address_space(1))) unsigned int*)g,
        (__attribute__((address_space(3))) unsigned int*)l, 16, 0, 0);
}

// ---------------- fused f32 -> bf16 (RNE) for all 5 tensors -----------------
__global__ __launch_bounds__(256) void convert_all(
    const float* __restrict__ h,  const float* __restrict__ wq,
    const float* __restrict__ wg, const float* __restrict__ wu,
    const float* __restrict__ wd,
    ushort_t* __restrict__ hb,  ushort_t* __restrict__ wqb,
    ushort_t* __restrict__ wgb, ushort_t* __restrict__ wub,
    ushort_t* __restrict__ wdb) {
    const int i = blockIdx.x * 256 + threadIdx.x;
    const float* src; ushort_t* dst; int off;
    if      (i <  262144) { src = h;  dst = hb;  off = i; }
    else if (i <  294912) { src = wq; dst = wqb; off = i - 262144; }
    else if (i <  557056) { src = wg; dst = wgb; off = i - 294912; }
    else if (i <  819200) { src = wu; dst = wub; off = i - 557056; }
    else                  { src = wd; dst = wdb; off = i - 819200; }
    const float4* p = (const float4*)src + (size_t)off * 2;
    const float4 a = p[0], b = p[1];
    uint4 o;
    o.x = (unsigned)f2bf_rne(a.x) | ((unsigned)f2bf_rne(a.y) << 16);
    o.y = (unsigned)f2bf_rne(a.z) | ((unsigned)f2bf_rne(a.w) << 16);
    o.z = (unsigned)f2bf_rne(b.x) | ((unsigned)f2bf_rne(b.y) << 16);
    o.w = (unsigned)f2bf_rne(b.z) | ((unsigned)f2bf_rne(b.w) << 16);
    ((uint4*)dst)[off] = o;
}

// ---------------- bf16 MFMA GEMM: C[M,N] = A[M,K] @ B[N,K]^T ----------------
// EPI 0: f32 = acc | 1: bf16 = silu(extra_bf16)*acc | 2: f32 = acc+extra_f32
// EPI 3: bf16 = acc   (EPI 2 may have Cout == extra: same-thread in-place add)
template<int BM, int BN, int WR, int WC, int FM, int FN, int EPI>
__global__ __launch_bounds__(256) void mfma_gemm(const ushort_t* __restrict__ A,
                                                 const ushort_t* __restrict__ B,
                                                 const void* __restrict__ extra,
                                                 void* __restrict__ Cout,
                                                 int M, int N, int K) {
    static_assert(WR * WC == 4 && WR * FM * 16 == BM && WC * FN * 16 == BN, "geom");
    __shared__ ushort_t As[BM * 32];
    __shared__ ushort_t Bs[BN * 32];
    const int tid = threadIdx.x;
    const int w = tid >> 6, lane = tid & 63;
    const int wr = w / WC, wc = w % WC;
    const int m0 = blockIdx.y * BM, n0 = blockIdx.x * BN;

    const int srow = (w << 4) + (lane >> 2);
    const int scol = (lane & 3) << 3;
    const ushort_t* Ag = &A[(size_t)(m0 + srow) * K + scol];
    const ushort_t* Bg = &B[(size_t)(n0 + srow) * K + scol];
    ushort_t* Al = &As[w << 9];
    ushort_t* Bl = &Bs[w << 9];

    const int frow = lane & 15;
    const int fcol = (lane >> 4) << 3;
    const ushort_t* Afr = &As[(size_t)(wr * FM * 16 + frow) * 32 + fcol];
    const ushort_t* Bfr = &Bs[(size_t)(wc * FN * 16 + frow) * 32 + fcol];

    f32x4 acc[FM][FN];
#pragma unroll
    for (int i = 0; i < FM; ++i)
#pragma unroll
        for (int j = 0; j < FN; ++j) acc[i][j] = (f32x4){0.f, 0.f, 0.f, 0.f};

    for (int k0 = 0; k0 < K; k0 += 32) {
        __syncthreads();
#pragma unroll
        for (int i = 0; i < BM / 64; ++i)
            gload_lds16(Ag + (size_t)i * 64 * K + k0, Al + i * 2048);
#pragma unroll
        for (int i = 0; i < BN / 64; ++i)
            gload_lds16(Bg + (size_t)i * 64 * K + k0, Bl + i * 2048);
        __syncthreads();

        bf16x8 af[FM], bfv[FN];
#pragma unroll
        for (int i = 0; i < FM; ++i) af[i] = *(const bf16x8*)(Afr + i * 512);
#pragma unroll
        for (int j = 0; j < FN; ++j) bfv[j] = *(const bf16x8*)(Bfr + j * 512);
#pragma unroll
        for (int i = 0; i < FM; ++i)
#pragma unroll
            for (int j = 0; j < FN; ++j)
                acc[i][j] = __builtin_amdgcn_mfma_f32_16x16x32_bf16(
                    af[i], bfv[j], acc[i][j], 0, 0, 0);
    }

    const int crow0 = m0 + wr * FM * 16 + ((lane >> 4) << 2);
    const int ccol0 = n0 + wc * FN * 16 + (lane & 15);
#pragma unroll
    for (int i = 0; i < FM; ++i)
#pragma unroll
        for (int j = 0; j < FN; ++j)
#pragma unroll
            for (int r = 0; r < 4; ++r) {
                const size_t off = (size_t)(crow0 + i * 16 + r) * N + ccol0 + j * 16;
                float v = acc[i][j][r];
                if (EPI == 1) {
                    const float gg = bf2f(((const ushort_t*)extra)[off]);
                    v *= gg / (1.f + __expf(-gg));
                    ((ushort_t*)Cout)[off] = f2bf_rne(v);
                } else if (EPI == 2) {
                    ((float*)Cout)[off] = v + ((const float*)extra)[off];
                } else if (EPI == 3) {
                    ((ushort_t*)Cout)[off] = f2bf_rne(v);
                } else {
                    ((float*)Cout)[off] = v;
                }
            }
}

// ---------------- act[i] = silu(g[i]) * u[i], in-place on u -----------------
__global__ __launch_bounds__(256) void silu_mul_inplace(const ushort_t* __restrict__ g,
                                                        ushort_t* __restrict__ u) {
    const int i = blockIdx.x * 256 + threadIdx.x;   // chunk of 8 bf16
    const uint4 gv = ((const uint4*)g)[i];
    const uint4 uv = ((const uint4*)u)[i];
    const unsigned gw[4] = {gv.x, gv.y, gv.z, gv.w};
    const unsigned uw[4] = {uv.x, uv.y, uv.z, uv.w};
    unsigned ow[4];
#pragma unroll
    for (int j = 0; j < 4; ++j) {
        const float g0 = bf2f((ushort_t)(gw[j] & 0xffff));
        const float g1 = bf2f((ushort_t)(gw[j] >> 16));
        const float u0 = bf2f((ushort_t)(uw[j] & 0xffff));
        const float u1 = bf2f((ushort_t)(uw[j] >> 16));
        const float v0 = g0 / (1.f + __expf(-g0)) * u0;
        const float v1 = g1 / (1.f + __expf(-g1)) * u1;
        ow[j] = (unsigned)f2bf_rne(v0) | ((unsigned)f2bf_rne(v1) << 16);
    }
    ((uint4*)u)[i] = (uint4){ow[0], ow[1], ow[2], ow[3]};
}

// ---------------- wave-parallel product-key routing (unchanged) --------------
__global__ __launch_bounds__(256) void topk_kernel(const float* __restrict__ q,
                                                   const float* __restrict__ keys,
                                                   int* __restrict__ eidx,
                                                   float* __restrict__ ewgt) {
    const int t = blockIdx.x;
    const int head = threadIdx.x >> 6;
    const int lane = threadIdx.x & 63;

    const float4* qx = (const float4*)&q[(size_t)t * 256 + head * 32];
    const float4* qy = (const float4*)&q[(size_t)t * 256 + 128 + head * 32];
    float4 qxv[8], qyv[8];
#pragma unroll
    for (int n = 0; n < 8; ++n) { qxv[n] = qx[n]; qyv[n] = qy[n]; }

    float cx0, cx1, cy0, cy1;
    {
        float s[4];
#pragma unroll
        for (int j = 0; j < 2; ++j) {
            const int k = 2 * lane + j;
            const float4* kx = (const float4*)&keys[(size_t)(((head << 7) | k) * 2 + 0) * 32];
            const float4* ky = (const float4*)&keys[(size_t)(((head << 7) | k) * 2 + 1) * 32];
            float sx = 0.f, sy = 0.f;
#pragma unroll
            for (int n = 0; n < 8; ++n) {
                const float4 a = qxv[n], b = kx[n];
                sx += a.x * b.x + a.y * b.y + a.z * b.z + a.w * b.w;
                const float4 c = qyv[n], d = ky[n];
                sy += c.x * d.x + c.y * d.y + c.z * d.z + c.w * d.w;
            }
            s[j * 2] = sx; s[j * 2 + 1] = sy;
        }
        cx0 = s[0]; cy0 = s[1]; cx1 = s[2]; cy1 = s[3];
    }

    float sx_mine = NINF, sy_mine = NINF;
    int sxi_mine = 0, syi_mine = 0;
    {
        float c0 = cx0, c1 = cx1;
#pragma unroll
        for (int it = 0; it < TOPK; ++it) {
            float bv; int bi;
            if (c1 > c0) { bv = c1; bi = 2 * lane + 1; } else { bv = c0; bi = 2 * lane; }
#pragma unroll
            for (int m = 1; m < 64; m <<= 1) {
                const float ov = __shfl_xor(bv, m);
                const int   oi = __shfl_xor(bi, m);
                if (ov > bv || (ov == bv && oi < bi)) { bv = ov; bi = oi; }
            }
            if (lane == it) { sx_mine = bv; sxi_mine = bi; }
            if (bi == 2 * lane) c0 = NINF;
            else if (bi == 2 * lane + 1) c1 = NINF;
        }
    }
    {
        float c0 = cy0, c1 = cy1;
#pragma unroll
        for (int it = 0; it < TOPK; ++it) {
            float bv; int bi;
            if (c1 > c0) { bv = c1; bi = 2 * lane + 1; } else { bv = c0; bi = 2 * lane; }
#pragma unroll
            for (int m = 1; m < 64; m <<= 1) {
                const float ov = __shfl_xor(bv, m);
                const int   oi = __shfl_xor(bi, m);
                if (ov > bv || (ov == bv && oi < bi)) { bv = ov; bi = oi; }
            }
            if (lane == it) { sy_mine = bv; syi_mine = bi; }
            if (bi == 2 * lane) c0 = NINF;
            else if (bi == 2 * lane + 1) c1 = NINF;
        }
    }

    const float sa = __shfl(sx_mine, lane >> 3);
    const int   ia = __shfl(sxi_mine, lane >> 3);
    const float sb = __shfl(sy_mine, lane & 7);
    const int   ib = __shfl(syi_mine, lane & 7);
    float cv = sa + sb;
    const int ci = ia * NKEYS + ib;

    float fs_mine = NINF; int fi_mine = 0;
#pragma unroll
    for (int it = 0; it < TOPK; ++it) {
        float bv = cv; int bp = lane; int bx = ci;
#pragma unroll
        for (int m = 1; m < 64; m <<= 1) {
            const float ov = __shfl_xor(bv, m);
            const int   op = __shfl_xor(bp, m);
            const int   ox = __shfl_xor(bx, m);
            if (ov > bv || (ov == bv && op < bp)) { bv = ov; bp = op; bx = ox; }
        }
        if (lane == it) { fs_mine = bv; fi_mine = bx; }
        if (lane == bp) cv = NINF;
    }

    float f[8];
#pragma unroll
    for (int j = 0; j < 8; ++j) f[j] = __shfl(fs_mine, j);
    float mx = f[0];
#pragma unroll
    for (int j = 1; j < 8; ++j) mx = fmaxf(mx, f[j]);
    float ssum = 0.f;
#pragma unroll
    for (int j = 0; j < 8; ++j) ssum += expf(f[j] - mx);
    if (lane < 8) {
        eidx[t * 32 + head * 8 + lane] = fi_mine;
        ewgt[t * 32 + head * 8 + lane] = expf(fs_mine - mx) / ssum;
    }
}

// ---------------- FUSED: gate GEMM + up GEMM + experts blocks ---------------
// 3072 blocks, pattern of 6 {E,E,G,E,E,U}:
//   b%6==2 -> gate GEMM block id b/6 of 512 (64x128 tile, writes G bf16)
//   b%6==5 -> up   GEMM block id b/6 of 512 (same geometry, writes U bf16)
//   else   -> expert block, token t = (b/6)*4 + (b%6 - (b%6>2)); estate -> OUT
// GEMM body identical to R10's gate path (block-uniform B/C pointer select).
__global__ __launch_bounds__(256) void fused3_kernel(
    const ushort_t* __restrict__ A,  const ushort_t* __restrict__ Bgate,
    const ushort_t* __restrict__ Bup, ushort_t* __restrict__ G,
    ushort_t* __restrict__ U,
    const float* __restrict__ hs, const float* __restrict__ down_embed,
    const float* __restrict__ up_embed, const int* __restrict__ eidx,
    const float* __restrict__ ewgt, float* __restrict__ estate) {
    __shared__ __align__(16) char smem[16896];
    const int b = blockIdx.x;
    const int tid = threadIdx.x;
    const int w = tid >> 6, lane = tid & 63;
    const int r6 = b % 6;

    if (r6 == 2 || r6 == 5) {
        // ---------------- GEMM path: BM=64 BN=128 WR=1 WC=4 FM=4 FN=2 -------
        const ushort_t* B = (r6 == 2) ? Bgate : Bup;
        ushort_t*      C  = (r6 == 2) ? G : U;
        const int id = b / 6;
        const int m0 = (id >> 4) * 64, n0 = (id & 15) * 128;
        const int N = INTER, K = DIM;
        ushort_t* As = (ushort_t*)smem;             // 4 KB
        ushort_t* Bs = (ushort_t*)(smem + 4096);    // 8 KB
        const int wc = w;                            // WR=1 -> wr=0
        const int srow = (w << 4) + (lane >> 2);
        const int scol = (lane & 3) << 3;
        const ushort_t* Ag = &A[(size_t)(m0 + srow) * K + scol];
        const ushort_t* Bg = &B[(size_t)(n0 + srow) * K + scol];
        ushort_t* Al = &As[w << 9];
        ushort_t* Bl = &Bs[w << 9];
        const int frow = lane & 15;
        const int fcol = (lane >> 4) << 3;
        const ushort_t* Afr = &As[(size_t)frow * 32 + fcol];
        const ushort_t* Bfr = &Bs[(size_t)(wc * 32 + frow) * 32 + fcol];

        f32x4 acc[4][2];
#pragma unroll
        for (int i = 0; i < 4; ++i)
#pragma unroll
            for (int j = 0; j < 2; ++j) acc[i][j] = (f32x4){0.f, 0.f, 0.f, 0.f};

        for (int k0 = 0; k0 < K; k0 += 32) {
            __syncthreads();
            gload_lds16(Ag + k0, Al);
#pragma unroll
            for (int i = 0; i < 2; ++i)
                gload_lds16(Bg + (size_t)i * 64 * K + k0, Bl + i * 2048);
            __syncthreads();

            bf16x8 af[4], bfv[2];
#pragma unroll
            for (int i = 0; i < 4; ++i) af[i] = *(const bf16x8*)(Afr + i * 512);
#pragma unroll
            for (int j = 0; j < 2; ++j) bfv[j] = *(const bf16x8*)(Bfr + j * 512);
#pragma unroll
            for (int i = 0; i < 4; ++i)
#pragma unroll
                for (int j = 0; j < 2; ++j)
                    acc[i][j] = __builtin_amdgcn_mfma_f32_16x16x32_bf16(
                        af[i], bfv[j], acc[i][j], 0, 0, 0);
        }

        const int crow0 = m0 + ((lane >> 4) << 2);
        const int ccol0 = n0 + wc * 32 + (lane & 15);
#pragma unroll
        for (int i = 0; i < 4; ++i)
#pragma unroll
            for (int j = 0; j < 2; ++j)
#pragma unroll
                for (int r = 0; r < 4; ++r) {
                    const size_t off = (size_t)(crow0 + i * 16 + r) * N + ccol0 + j * 16;
                    C[off] = f2bf_rne(acc[i][j][r]);
                }
    } else {
        // ---------------- experts path: exact R10 body, estate -> OUT -------
        const int t = (b / 6) * 4 + r6 - (r6 > 2 ? 1 : 0);
        float4 (*partial)[256] = (float4(*)[256])smem;      // 16 KB
        int*   eid = (int*)(smem + 16384);                  // 128 B
        float* wl  = (float*)(smem + 16512);                // 128 B

        if (tid < 32) { eid[tid] = eidx[t * 32 + tid]; wl[tid] = ewgt[t * 32 + tid]; }

        const float4* hs4 = (const float4*)hs + (size_t)t * 256;
        float4 h[4];
#pragma unroll
        for (int i = 0; i < 4; ++i) h[i] = hs4[i * 64 + lane];

        const float4* de4 = (const float4*)down_embed;
        const float4* ue4 = (const float4*)up_embed;
        __syncthreads();

        float4 acc[4];
#pragma unroll
        for (int i = 0; i < 4; ++i) acc[i] = (float4){0.f, 0.f, 0.f, 0.f};

        float4 d[4], u[4], nd[4], nu[4];
        {
            const size_t bb = (size_t)eid[w * 8] * 256;
#pragma unroll
            for (int i = 0; i < 4; ++i) { d[i] = de4[bb + i * 64 + lane]; u[i] = ue4[bb + i * 64 + lane]; }
        }
#pragma unroll
        for (int jj = 0; jj < 8; ++jj) {
            if (jj < 7) {
                const size_t bb = (size_t)eid[w * 8 + jj + 1] * 256;
#pragma unroll
                for (int i = 0; i < 4; ++i) { nd[i] = de4[bb + i * 64 + lane]; nu[i] = ue4[bb + i * 64 + lane]; }
            }
            float s = 0.f;
#pragma unroll
            for (int i = 0; i < 4; ++i)
                s += h[i].x * d[i].x + h[i].y * d[i].y + h[i].z * d[i].z + h[i].w * d[i].w;
#pragma unroll
            for (int m = 1; m < 64; m <<= 1) s += __shfl_xor(s, m);
            const float c = (s / (1.f + __expf(-s))) * wl[w * 8 + jj];
#pragma unroll
            for (int i = 0; i < 4; ++i) {
                acc[i].x += c * u[i].x; acc[i].y += c * u[i].y;
                acc[i].z += c * u[i].z; acc[i].w += c * u[i].w;
            }
            if (jj < 7) {
#pragma unroll
                for (int i = 0; i < 4; ++i) { d[i] = nd[i]; u[i] = nu[i]; }
            }
        }

#pragma unroll
        for (int i = 0; i < 4; ++i) partial[w][i * 64 + lane] = acc[i];
        __syncthreads();

        const float4 p0 = partial[0][tid], p1 = partial[1][tid];
        const float4 p2 = partial[2][tid], p3 = partial[3][tid];
        float4 o;
        o.x = p0.x + p1.x + p2.x + p3.x;
        o.y = p0.y + p1.y + p2.y + p3.y;
        o.z = p0.z + p1.z + p2.z + p3.z;
        o.w = p0.w + p1.w + p2.w + p3.w;
        ((float4*)estate)[(size_t)t * 256 + tid] = o;
    }
}

// ---------------------------------------------------------------------------
extern "C" void kernel_launch(void* const* d_in, const int* in_sizes, int n_in,
                              void* d_out, int out_size, void* d_ws, size_t ws_size,
                              hipStream_t stream) {
    (void)in_sizes; (void)n_in; (void)out_size; (void)ws_size;
    const float* hidden = (const float*)d_in[0];
    const float* wq     = (const float*)d_in[1];
    const float* keys   = (const float*)d_in[2];
    const float* down_e = (const float*)d_in[3];
    const float* up_e   = (const float*)d_in[4];
    const float* wgate  = (const float*)d_in[5];
    const float* wup    = (const float*)d_in[6];
    const float* wdown  = (const float*)d_in[7];
    float* out = (float*)d_out;
    char* ws = (char*)d_ws;

    // workspace layout: EXACT round-10 (passed). act holds raw u, then the
    // in-place silu pass turns it into act; estate lives in d_out.
    ushort_t* hb  = (ushort_t*)(ws);                     // 4 MB
    ushort_t* wqb = (ushort_t*)(ws + (4u << 20));        // 0.5 MB
    ushort_t* wgb = (ushort_t*)(ws + (4608u << 10));     // 4 MB
    ushort_t* wub = (ushort_t*)(ws + (8704u << 10));     // 4 MB
    ushort_t* wdb = (ushort_t*)(ws + (12800u << 10));    // 4 MB
    float*    q   = (float*)   (ws + (16896u << 10));    // 2 MB
    ushort_t* act = (ushort_t*)(ws + (18944u << 10));    // 8 MB (raw u, then act)
    ushort_t* g   = (ushort_t*)(ws + (27136u << 10));    // 8 MB
    float*    wgt = (float*)   (ws + (35328u << 10));    // 0.25 MB
    int*     eidx = (int*)     (ws + (35584u << 10));    // 0.25 MB
    float* estate = out;                                 // 8 MB, in d_out

    convert_all<<<4224, 256, 0, stream>>>(hidden, wq, wgate, wup, wdown,
                                          hb, wqb, wgb, wub, wdb);

    // 1) q = hidden @ wq^T  (2048 x 256 x 1024), f32 out for routing
    mfma_gemm<64, 64, 2, 2, 2, 2, 0><<<dim3(4, 32), 256, 0, stream>>>(
        hb, wqb, nullptr, q, TOKENS, 256, DIM);
    // 2) routing (wave-parallel)
    topk_kernel<<<TOKENS, 256, 0, stream>>>(q, keys, eidx, wgt);
    // 3+4+5 FUSED) g = h@wgate^T || u = h@wup^T || experts -> out
    fused3_kernel<<<3072, 256, 0, stream>>>(
        hb, wgb, wub, g, act, hidden, down_e, up_e, eidx, wgt, estate);
    // 4b) act = silu(g) * u, in-place on the u buffer
    silu_mul_inplace<<<2048, 256, 0, stream>>>(g, act);
    // 6) out = act @ wdown^T + out(=estate), in-place same-thread add
    mfma_gemm<64, 128, 1, 4, 4, 2, 2><<<dim3(8, 32), 256, 0, stream>>>(
        act, wdb, estate, out, TOKENS, DIM, INTER);
}

// Round 12
// 204.646 us; speedup vs baseline: 1.1906x; 1.0658x over previous
//
#include <hip/hip_runtime.h>
#include <hip/hip_bf16.h>
#include <math.h>

// ---------------------------------------------------------------------------
// DogeCDMoE round 12: EXACT round-11 file (passed, 218.1us) with ONE delta:
// down-GEMM tile 64x128 -> 64x64, grid(8,32)->(16,32) = 512 blocks = 2/CU.
// (R11 arithmetic audit: down-GEMM was ~60-80us at 256 blocks = 1 block/CU,
// the same pathology R7 fixed for gate/up. <64,64,2,2,2,2> geometry proven in
// qgemm since R2; EPI2 proven since R9; per-element K order unchanged ->
// bit-identical output.)
// ---------------------------------------------------------------------------

#define TOKENS 2048
#define DIM    1024
#define INTER  2048
#define NKEYS  128
#define TOPK   8
#define HEADS  4
#define NINF  -3.4e38f

typedef unsigned short ushort_t;
typedef __attribute__((ext_vector_type(8))) short bf16x8;
typedef __attribute__((ext_vector_type(4))) float f32x4;

__device__ __forceinline__ float bf2f(ushort_t u) {
    unsigned int x = (unsigned int)u << 16;
    float f; __builtin_memcpy(&f, &x, 4); return f;
}
__device__ __forceinline__ ushort_t f2bf_rne(float f) {
    unsigned int x; __builtin_memcpy(&x, &f, 4);
    x += 0x7fffu + ((x >> 16) & 1u);
    return (ushort_t)(x >> 16);
}
__device__ __forceinline__ void gload_lds16(const void* g, void* l) {
    __builtin_amdgcn_global_load_lds(
        (const __attribute__((address_space(1))) unsigned int*)g,
        (__attribute__((address_space(3))) unsigned int*)l, 16, 0, 0);
}

// ---------------- fused f32 -> bf16 (RNE) for all 5 tensors -----------------
__global__ __launch_bounds__(256) void convert_all(
    const float* __restrict__ h,  const float* __restrict__ wq,
    const float* __restrict__ wg, const float* __restrict__ wu,
    const float* __restrict__ wd,
    ushort_t* __restrict__ hb,  ushort_t* __restrict__ wqb,
    ushort_t* __restrict__ wgb, ushort_t* __restrict__ wub,
    ushort_t* __restrict__ wdb) {
    const int i = blockIdx.x * 256 + threadIdx.x;
    const float* src; ushort_t* dst; int off;
    if      (i <  262144) { src = h;  dst = hb;  off = i; }
    else if (i <  294912) { src = wq; dst = wqb; off = i - 262144; }
    else if (i <  557056) { src = wg; dst = wgb; off = i - 294912; }
    else if (i <  819200) { src = wu; dst = wub; off = i - 557056; }
    else                  { src = wd; dst = wdb; off = i - 819200; }
    const float4* p = (const float4*)src + (size_t)off * 2;
    const float4 a = p[0], b = p[1];
    uint4 o;
    o.x = (unsigned)f2bf_rne(a.x) | ((unsigned)f2bf_rne(a.y) << 16);
    o.y = (unsigned)f2bf_rne(a.z) | ((unsigned)f2bf_rne(a.w) << 16);
    o.z = (unsigned)f2bf_rne(b.x) | ((unsigned)f2bf_rne(b.y) << 16);
    o.w = (unsigned)f2bf_rne(b.z) | ((unsigned)f2bf_rne(b.w) << 16);
    ((uint4*)dst)[off] = o;
}

// ---------------- bf16 MFMA GEMM: C[M,N] = A[M,K] @ B[N,K]^T ----------------
// EPI 0: f32 = acc | 1: bf16 = silu(extra_bf16)*acc | 2: f32 = acc+extra_f32
// EPI 3: bf16 = acc   (EPI 2 may have Cout == extra: same-thread in-place add)
template<int BM, int BN, int WR, int WC, int FM, int FN, int EPI>
__global__ __launch_bounds__(256) void mfma_gemm(const ushort_t* __restrict__ A,
                                                 const ushort_t* __restrict__ B,
                                                 const void* __restrict__ extra,
                                                 void* __restrict__ Cout,
                                                 int M, int N, int K) {
    static_assert(WR * WC == 4 && WR * FM * 16 == BM && WC * FN * 16 == BN, "geom");
    __shared__ ushort_t As[BM * 32];
    __shared__ ushort_t Bs[BN * 32];
    const int tid = threadIdx.x;
    const int w = tid >> 6, lane = tid & 63;
    const int wr = w / WC, wc = w % WC;
    const int m0 = blockIdx.y * BM, n0 = blockIdx.x * BN;

    const int srow = (w << 4) + (lane >> 2);
    const int scol = (lane & 3) << 3;
    const ushort_t* Ag = &A[(size_t)(m0 + srow) * K + scol];
    const ushort_t* Bg = &B[(size_t)(n0 + srow) * K + scol];
    ushort_t* Al = &As[w << 9];
    ushort_t* Bl = &Bs[w << 9];

    const int frow = lane & 15;
    const int fcol = (lane >> 4) << 3;
    const ushort_t* Afr = &As[(size_t)(wr * FM * 16 + frow) * 32 + fcol];
    const ushort_t* Bfr = &Bs[(size_t)(wc * FN * 16 + frow) * 32 + fcol];

    f32x4 acc[FM][FN];
#pragma unroll
    for (int i = 0; i < FM; ++i)
#pragma unroll
        for (int j = 0; j < FN; ++j) acc[i][j] = (f32x4){0.f, 0.f, 0.f, 0.f};

    for (int k0 = 0; k0 < K; k0 += 32) {
        __syncthreads();
#pragma unroll
        for (int i = 0; i < BM / 64; ++i)
            gload_lds16(Ag + (size_t)i * 64 * K + k0, Al + i * 2048);
#pragma unroll
        for (int i = 0; i < BN / 64; ++i)
            gload_lds16(Bg + (size_t)i * 64 * K + k0, Bl + i * 2048);
        __syncthreads();

        bf16x8 af[FM], bfv[FN];
#pragma unroll
        for (int i = 0; i < FM; ++i) af[i] = *(const bf16x8*)(Afr + i * 512);
#pragma unroll
        for (int j = 0; j < FN; ++j) bfv[j] = *(const bf16x8*)(Bfr + j * 512);
#pragma unroll
        for (int i = 0; i < FM; ++i)
#pragma unroll
            for (int j = 0; j < FN; ++j)
                acc[i][j] = __builtin_amdgcn_mfma_f32_16x16x32_bf16(
                    af[i], bfv[j], acc[i][j], 0, 0, 0);
    }

    const int crow0 = m0 + wr * FM * 16 + ((lane >> 4) << 2);
    const int ccol0 = n0 + wc * FN * 16 + (lane & 15);
#pragma unroll
    for (int i = 0; i < FM; ++i)
#pragma unroll
        for (int j = 0; j < FN; ++j)
#pragma unroll
            for (int r = 0; r < 4; ++r) {
                const size_t off = (size_t)(crow0 + i * 16 + r) * N + ccol0 + j * 16;
                float v = acc[i][j][r];
                if (EPI == 1) {
                    const float gg = bf2f(((const ushort_t*)extra)[off]);
                    v *= gg / (1.f + __expf(-gg));
                    ((ushort_t*)Cout)[off] = f2bf_rne(v);
                } else if (EPI == 2) {
                    ((float*)Cout)[off] = v + ((const float*)extra)[off];
                } else if (EPI == 3) {
                    ((ushort_t*)Cout)[off] = f2bf_rne(v);
                } else {
                    ((float*)Cout)[off] = v;
                }
            }
}

// ---------------- act[i] = silu(g[i]) * u[i], in-place on u -----------------
__global__ __launch_bounds__(256) void silu_mul_inplace(const ushort_t* __restrict__ g,
                                                        ushort_t* __restrict__ u) {
    const int i = blockIdx.x * 256 + threadIdx.x;   // chunk of 8 bf16
    const uint4 gv = ((const uint4*)g)[i];
    const uint4 uv = ((const uint4*)u)[i];
    const unsigned gw[4] = {gv.x, gv.y, gv.z, gv.w};
    const unsigned uw[4] = {uv.x, uv.y, uv.z, uv.w};
    unsigned ow[4];
#pragma unroll
    for (int j = 0; j < 4; ++j) {
        const float g0 = bf2f((ushort_t)(gw[j] & 0xffff));
        const float g1 = bf2f((ushort_t)(gw[j] >> 16));
        const float u0 = bf2f((ushort_t)(uw[j] & 0xffff));
        const float u1 = bf2f((ushort_t)(uw[j] >> 16));
        const float v0 = g0 / (1.f + __expf(-g0)) * u0;
        const float v1 = g1 / (1.f + __expf(-g1)) * u1;
        ow[j] = (unsigned)f2bf_rne(v0) | ((unsigned)f2bf_rne(v1) << 16);
    }
    ((uint4*)u)[i] = (uint4){ow[0], ow[1], ow[2], ow[3]};
}

// ---------------- wave-parallel product-key routing (unchanged) --------------
__global__ __launch_bounds__(256) void topk_kernel(const float* __restrict__ q,
                                                   const float* __restrict__ keys,
                                                   int* __restrict__ eidx,
                                                   float* __restrict__ ewgt) {
    const int t = blockIdx.x;
    const int head = threadIdx.x >> 6;
    const int lane = threadIdx.x & 63;

    const float4* qx = (const float4*)&q[(size_t)t * 256 + head * 32];
    const float4* qy = (const float4*)&q[(size_t)t * 256 + 128 + head * 32];
    float4 qxv[8], qyv[8];
#pragma unroll
    for (int n = 0; n < 8; ++n) { qxv[n] = qx[n]; qyv[n] = qy[n]; }

    float cx0, cx1, cy0, cy1;
    {
        float s[4];
#pragma unroll
        for (int j = 0; j < 2; ++j) {
            const int k = 2 * lane + j;
            const float4* kx = (const float4*)&keys[(size_t)(((head << 7) | k) * 2 + 0) * 32];
            const float4* ky = (const float4*)&keys[(size_t)(((head << 7) | k) * 2 + 1) * 32];
            float sx = 0.f, sy = 0.f;
#pragma unroll
            for (int n = 0; n < 8; ++n) {
                const float4 a = qxv[n], b = kx[n];
                sx += a.x * b.x + a.y * b.y + a.z * b.z + a.w * b.w;
                const float4 c = qyv[n], d = ky[n];
                sy += c.x * d.x + c.y * d.y + c.z * d.z + c.w * d.w;
            }
            s[j * 2] = sx; s[j * 2 + 1] = sy;
        }
        cx0 = s[0]; cy0 = s[1]; cx1 = s[2]; cy1 = s[3];
    }

    float sx_mine = NINF, sy_mine = NINF;
    int sxi_mine = 0, syi_mine = 0;
    {
        float c0 = cx0, c1 = cx1;
#pragma unroll
        for (int it = 0; it < TOPK; ++it) {
            float bv; int bi;
            if (c1 > c0) { bv = c1; bi = 2 * lane + 1; } else { bv = c0; bi = 2 * lane; }
#pragma unroll
            for (int m = 1; m < 64; m <<= 1) {
                const float ov = __shfl_xor(bv, m);
                const int   oi = __shfl_xor(bi, m);
                if (ov > bv || (ov == bv && oi < bi)) { bv = ov; bi = oi; }
            }
            if (lane == it) { sx_mine = bv; sxi_mine = bi; }
            if (bi == 2 * lane) c0 = NINF;
            else if (bi == 2 * lane + 1) c1 = NINF;
        }
    }
    {
        float c0 = cy0, c1 = cy1;
#pragma unroll
        for (int it = 0; it < TOPK; ++it) {
            float bv; int bi;
            if (c1 > c0) { bv = c1; bi = 2 * lane + 1; } else { bv = c0; bi = 2 * lane; }
#pragma unroll
            for (int m = 1; m < 64; m <<= 1) {
                const float ov = __shfl_xor(bv, m);
                const int   oi = __shfl_xor(bi, m);
                if (ov > bv || (ov == bv && oi < bi)) { bv = ov; bi = oi; }
            }
            if (lane == it) { sy_mine = bv; syi_mine = bi; }
            if (bi == 2 * lane) c0 = NINF;
            else if (bi == 2 * lane + 1) c1 = NINF;
        }
    }

    const float sa = __shfl(sx_mine, lane >> 3);
    const int   ia = __shfl(sxi_mine, lane >> 3);
    const float sb = __shfl(sy_mine, lane & 7);
    const int   ib = __shfl(syi_mine, lane & 7);
    float cv = sa + sb;
    const int ci = ia * NKEYS + ib;

    float fs_mine = NINF; int fi_mine = 0;
#pragma unroll
    for (int it = 0; it < TOPK; ++it) {
        float bv = cv; int bp = lane; int bx = ci;
#pragma unroll
        for (int m = 1; m < 64; m <<= 1) {
            const float ov = __shfl_xor(bv, m);
            const int   op = __shfl_xor(bp, m);
            const int   ox = __shfl_xor(bx, m);
            if (ov > bv || (ov == bv && op < bp)) { bv = ov; bp = op; bx = ox; }
        }
        if (lane == it) { fs_mine = bv; fi_mine = bx; }
        if (lane == bp) cv = NINF;
    }

    float f[8];
#pragma unroll
    for (int j = 0; j < 8; ++j) f[j] = __shfl(fs_mine, j);
    float mx = f[0];
#pragma unroll
    for (int j = 1; j < 8; ++j) mx = fmaxf(mx, f[j]);
    float ssum = 0.f;
#pragma unroll
    for (int j = 0; j < 8; ++j) ssum += expf(f[j] - mx);
    if (lane < 8) {
        eidx[t * 32 + head * 8 + lane] = fi_mine;
        ewgt[t * 32 + head * 8 + lane] = expf(fs_mine - mx) / ssum;
    }
}

// ---------------- FUSED: gate GEMM + up GEMM + experts blocks (unchanged) ---
__global__ __launch_bounds__(256) void fused3_kernel(
    const ushort_t* __restrict__ A,  const ushort_t* __restrict__ Bgate,
    const ushort_t* __restrict__ Bup, ushort_t* __restrict__ G,
    ushort_t* __restrict__ U,
    const float* __restrict__ hs, const float* __restrict__ down_embed,
    const float* __restrict__ up_embed, const int* __restrict__ eidx,
    const float* __restrict__ ewgt, float* __restrict__ estate) {
    __shared__ __align__(16) char smem[16896];
    const int b = blockIdx.x;
    const int tid = threadIdx.x;
    const int w = tid >> 6, lane = tid & 63;
    const int r6 = b % 6;

    if (r6 == 2 || r6 == 5) {
        const ushort_t* B = (r6 == 2) ? Bgate : Bup;
        ushort_t*      C  = (r6 == 2) ? G : U;
        const int id = b / 6;
        const int m0 = (id >> 4) * 64, n0 = (id & 15) * 128;
        const int N = INTER, K = DIM;
        ushort_t* As = (ushort_t*)smem;             // 4 KB
        ushort_t* Bs = (ushort_t*)(smem + 4096);    // 8 KB
        const int wc = w;                            // WR=1 -> wr=0
        const int srow = (w << 4) + (lane >> 2);
        const int scol = (lane & 3) << 3;
        const ushort_t* Ag = &A[(size_t)(m0 + srow) * K + scol];
        const ushort_t* Bg = &B[(size_t)(n0 + srow) * K + scol];
        ushort_t* Al = &As[w << 9];
        ushort_t* Bl = &Bs[w << 9];
        const int frow = lane & 15;
        const int fcol = (lane >> 4) << 3;
        const ushort_t* Afr = &As[(size_t)frow * 32 + fcol];
        const ushort_t* Bfr = &Bs[(size_t)(wc * 32 + frow) * 32 + fcol];

        f32x4 acc[4][2];
#pragma unroll
        for (int i = 0; i < 4; ++i)
#pragma unroll
            for (int j = 0; j < 2; ++j) acc[i][j] = (f32x4){0.f, 0.f, 0.f, 0.f};

        for (int k0 = 0; k0 < K; k0 += 32) {
            __syncthreads();
            gload_lds16(Ag + k0, Al);
#pragma unroll
            for (int i = 0; i < 2; ++i)
                gload_lds16(Bg + (size_t)i * 64 * K + k0, Bl + i * 2048);
            __syncthreads();

            bf16x8 af[4], bfv[2];
#pragma unroll
            for (int i = 0; i < 4; ++i) af[i] = *(const bf16x8*)(Afr + i * 512);
#pragma unroll
            for (int j = 0; j < 2; ++j) bfv[j] = *(const bf16x8*)(Bfr + j * 512);
#pragma unroll
            for (int i = 0; i < 4; ++i)
#pragma unroll
                for (int j = 0; j < 2; ++j)
                    acc[i][j] = __builtin_amdgcn_mfma_f32_16x16x32_bf16(
                        af[i], bfv[j], acc[i][j], 0, 0, 0);
        }

        const int crow0 = m0 + ((lane >> 4) << 2);
        const int ccol0 = n0 + wc * 32 + (lane & 15);
#pragma unroll
        for (int i = 0; i < 4; ++i)
#pragma unroll
            for (int j = 0; j < 2; ++j)
#pragma unroll
                for (int r = 0; r < 4; ++r) {
                    const size_t off = (size_t)(crow0 + i * 16 + r) * N + ccol0 + j * 16;
                    C[off] = f2bf_rne(acc[i][j][r]);
                }
    } else {
        const int t = (b / 6) * 4 + r6 - (r6 > 2 ? 1 : 0);
        float4 (*partial)[256] = (float4(*)[256])smem;      // 16 KB
        int*   eid = (int*)(smem + 16384);                  // 128 B
        float* wl  = (float*)(smem + 16512);                // 128 B

        if (tid < 32) { eid[tid] = eidx[t * 32 + tid]; wl[tid] = ewgt[t * 32 + tid]; }

        const float4* hs4 = (const float4*)hs + (size_t)t * 256;
        float4 h[4];
#pragma unroll
        for (int i = 0; i < 4; ++i) h[i] = hs4[i * 64 + lane];

        const float4* de4 = (const float4*)down_embed;
        const float4* ue4 = (const float4*)up_embed;
        __syncthreads();

        float4 acc[4];
#pragma unroll
        for (int i = 0; i < 4; ++i) acc[i] = (float4){0.f, 0.f, 0.f, 0.f};

        float4 d[4], u[4], nd[4], nu[4];
        {
            const size_t bb = (size_t)eid[w * 8] * 256;
#pragma unroll
            for (int i = 0; i < 4; ++i) { d[i] = de4[bb + i * 64 + lane]; u[i] = ue4[bb + i * 64 + lane]; }
        }
#pragma unroll
        for (int jj = 0; jj < 8; ++jj) {
            if (jj < 7) {
                const size_t bb = (size_t)eid[w * 8 + jj + 1] * 256;
#pragma unroll
                for (int i = 0; i < 4; ++i) { nd[i] = de4[bb + i * 64 + lane]; nu[i] = ue4[bb + i * 64 + lane]; }
            }
            float s = 0.f;
#pragma unroll
            for (int i = 0; i < 4; ++i)
                s += h[i].x * d[i].x + h[i].y * d[i].y + h[i].z * d[i].z + h[i].w * d[i].w;
#pragma unroll
            for (int m = 1; m < 64; m <<= 1) s += __shfl_xor(s, m);
            const float c = (s / (1.f + __expf(-s))) * wl[w * 8 + jj];
#pragma unroll
            for (int i = 0; i < 4; ++i) {
                acc[i].x += c * u[i].x; acc[i].y += c * u[i].y;
                acc[i].z += c * u[i].z; acc[i].w += c * u[i].w;
            }
            if (jj < 7) {
#pragma unroll
                for (int i = 0; i < 4; ++i) { d[i] = nd[i]; u[i] = nu[i]; }
            }
        }

#pragma unroll
        for (int i = 0; i < 4; ++i) partial[w][i * 64 + lane] = acc[i];
        __syncthreads();

        const float4 p0 = partial[0][tid], p1 = partial[1][tid];
        const float4 p2 = partial[2][tid], p3 = partial[3][tid];
        float4 o;
        o.x = p0.x + p1.x + p2.x + p3.x;
        o.y = p0.y + p1.y + p2.y + p3.y;
        o.z = p0.z + p1.z + p2.z + p3.z;
        o.w = p0.w + p1.w + p2.w + p3.w;
        ((float4*)estate)[(size_t)t * 256 + tid] = o;
    }
}

// ---------------------------------------------------------------------------
extern "C" void kernel_launch(void* const* d_in, const int* in_sizes, int n_in,
                              void* d_out, int out_size, void* d_ws, size_t ws_size,
                              hipStream_t stream) {
    (void)in_sizes; (void)n_in; (void)out_size; (void)ws_size;
    const float* hidden = (const float*)d_in[0];
    const float* wq     = (const float*)d_in[1];
    const float* keys   = (const float*)d_in[2];
    const float* down_e = (const float*)d_in[3];
    const float* up_e   = (const float*)d_in[4];
    const float* wgate  = (const float*)d_in[5];
    const float* wup    = (const float*)d_in[6];
    const float* wdown  = (const float*)d_in[7];
    float* out = (float*)d_out;
    char* ws = (char*)d_ws;

    // workspace layout: EXACT round-11 (passed).
    ushort_t* hb  = (ushort_t*)(ws);                     // 4 MB
    ushort_t* wqb = (ushort_t*)(ws + (4u << 20));        // 0.5 MB
    ushort_t* wgb = (ushort_t*)(ws + (4608u << 10));     // 4 MB
    ushort_t* wub = (ushort_t*)(ws + (8704u << 10));     // 4 MB
    ushort_t* wdb = (ushort_t*)(ws + (12800u << 10));    // 4 MB
    float*    q   = (float*)   (ws + (16896u << 10));    // 2 MB
    ushort_t* act = (ushort_t*)(ws + (18944u << 10));    // 8 MB (raw u, then act)
    ushort_t* g   = (ushort_t*)(ws + (27136u << 10));    // 8 MB
    float*    wgt = (float*)   (ws + (35328u << 10));    // 0.25 MB
    int*     eidx = (int*)     (ws + (35584u << 10));    // 0.25 MB
    float* estate = out;                                 // 8 MB, in d_out

    convert_all<<<4224, 256, 0, stream>>>(hidden, wq, wgate, wup, wdown,
                                          hb, wqb, wgb, wub, wdb);

    // 1) q = hidden @ wq^T  (2048 x 256 x 1024), f32 out for routing
    mfma_gemm<64, 64, 2, 2, 2, 2, 0><<<dim3(4, 32), 256, 0, stream>>>(
        hb, wqb, nullptr, q, TOKENS, 256, DIM);
    // 2) routing (wave-parallel)
    topk_kernel<<<TOKENS, 256, 0, stream>>>(q, keys, eidx, wgt);
    // 3+4+5 FUSED) g = h@wgate^T || u = h@wup^T || experts -> out
    fused3_kernel<<<3072, 256, 0, stream>>>(
        hb, wgb, wub, g, act, hidden, down_e, up_e, eidx, wgt, estate);
    // 4b) act = silu(g) * u, in-place on the u buffer
    silu_mul_inplace<<<2048, 256, 0, stream>>>(g, act);
    // 6) out = act @ wdown^T + out(=estate)  [DELTA: 64x64 tile, 512 blocks]
    mfma_gemm<64, 64, 2, 2, 2, 2, 2><<<dim3(16, 32), 256, 0, stream>>>(
        act, wdb, estate, out, TOKENS, DIM, INTER);
}

// Round 13
// 190.893 us; speedup vs baseline: 1.2764x; 1.0720x over previous
//
#include <hip/hip_runtime.h>
#include <hip/hip_bf16.h>
#include <math.h>

// ---------------------------------------------------------------------------
// DogeCDMoE round 13: EXACT round-12 file (passed, 204.6us) with ONE lever:
// bf16 expert tables. deb/ueb (64 MB, L3-resident) are converted per-call by
// blocks FUSED into the topk launch (independent work), and fused3's expert
// path reads bf16 rows (half the logical gather bytes; repeats hit L3).
// Guard: requires 99 MB workspace -> host-side branch on ws_size; fallback
// is the exact R12 sequence (no crash risk if ws is small).
// ---------------------------------------------------------------------------

#define TOKENS 2048
#define DIM    1024
#define INTER  2048
#define NKEYS  128
#define TOPK   8
#define HEADS  4
#define NINF  -3.4e38f

typedef unsigned short ushort_t;
typedef __attribute__((ext_vector_type(8))) short bf16x8;
typedef __attribute__((ext_vector_type(4))) float f32x4;

__device__ __forceinline__ float bf2f(ushort_t u) {
    unsigned int x = (unsigned int)u << 16;
    float f; __builtin_memcpy(&f, &x, 4); return f;
}
__device__ __forceinline__ ushort_t f2bf_rne(float f) {
    unsigned int x; __builtin_memcpy(&x, &f, 4);
    x += 0x7fffu + ((x >> 16) & 1u);
    return (ushort_t)(x >> 16);
}
__device__ __forceinline__ void gload_lds16(const void* g, void* l) {
    __builtin_amdgcn_global_load_lds(
        (const __attribute__((address_space(1))) unsigned int*)g,
        (__attribute__((address_space(3))) unsigned int*)l, 16, 0, 0);
}

// ---------------- fused f32 -> bf16 (RNE) for all 5 tensors -----------------
__global__ __launch_bounds__(256) void convert_all(
    const float* __restrict__ h,  const float* __restrict__ wq,
    const float* __restrict__ wg, const float* __restrict__ wu,
    const float* __restrict__ wd,
    ushort_t* __restrict__ hb,  ushort_t* __restrict__ wqb,
    ushort_t* __restrict__ wgb, ushort_t* __restrict__ wub,
    ushort_t* __restrict__ wdb) {
    const int i = blockIdx.x * 256 + threadIdx.x;
    const float* src; ushort_t* dst; int off;
    if      (i <  262144) { src = h;  dst = hb;  off = i; }
    else if (i <  294912) { src = wq; dst = wqb; off = i - 262144; }
    else if (i <  557056) { src = wg; dst = wgb; off = i - 294912; }
    else if (i <  819200) { src = wu; dst = wub; off = i - 557056; }
    else                  { src = wd; dst = wdb; off = i - 819200; }
    const float4* p = (const float4*)src + (size_t)off * 2;
    const float4 a = p[0], b = p[1];
    uint4 o;
    o.x = (unsigned)f2bf_rne(a.x) | ((unsigned)f2bf_rne(a.y) << 16);
    o.y = (unsigned)f2bf_rne(a.z) | ((unsigned)f2bf_rne(a.w) << 16);
    o.z = (unsigned)f2bf_rne(b.x) | ((unsigned)f2bf_rne(b.y) << 16);
    o.w = (unsigned)f2bf_rne(b.z) | ((unsigned)f2bf_rne(b.w) << 16);
    ((uint4*)dst)[off] = o;
}

// ---------------- bf16 MFMA GEMM: C[M,N] = A[M,K] @ B[N,K]^T ----------------
// EPI 0: f32 = acc | 1: bf16 = silu(extra_bf16)*acc | 2: f32 = acc+extra_f32
// EPI 3: bf16 = acc   (EPI 2 may have Cout == extra: same-thread in-place add)
template<int BM, int BN, int WR, int WC, int FM, int FN, int EPI>
__global__ __launch_bounds__(256) void mfma_gemm(const ushort_t* __restrict__ A,
                                                 const ushort_t* __restrict__ B,
                                                 const void* __restrict__ extra,
                                                 void* __restrict__ Cout,
                                                 int M, int N, int K) {
    static_assert(WR * WC == 4 && WR * FM * 16 == BM && WC * FN * 16 == BN, "geom");
    __shared__ ushort_t As[BM * 32];
    __shared__ ushort_t Bs[BN * 32];
    const int tid = threadIdx.x;
    const int w = tid >> 6, lane = tid & 63;
    const int wr = w / WC, wc = w % WC;
    const int m0 = blockIdx.y * BM, n0 = blockIdx.x * BN;

    const int srow = (w << 4) + (lane >> 2);
    const int scol = (lane & 3) << 3;
    const ushort_t* Ag = &A[(size_t)(m0 + srow) * K + scol];
    const ushort_t* Bg = &B[(size_t)(n0 + srow) * K + scol];
    ushort_t* Al = &As[w << 9];
    ushort_t* Bl = &Bs[w << 9];

    const int frow = lane & 15;
    const int fcol = (lane >> 4) << 3;
    const ushort_t* Afr = &As[(size_t)(wr * FM * 16 + frow) * 32 + fcol];
    const ushort_t* Bfr = &Bs[(size_t)(wc * FN * 16 + frow) * 32 + fcol];

    f32x4 acc[FM][FN];
#pragma unroll
    for (int i = 0; i < FM; ++i)
#pragma unroll
        for (int j = 0; j < FN; ++j) acc[i][j] = (f32x4){0.f, 0.f, 0.f, 0.f};

    for (int k0 = 0; k0 < K; k0 += 32) {
        __syncthreads();
#pragma unroll
        for (int i = 0; i < BM / 64; ++i)
            gload_lds16(Ag + (size_t)i * 64 * K + k0, Al + i * 2048);
#pragma unroll
        for (int i = 0; i < BN / 64; ++i)
            gload_lds16(Bg + (size_t)i * 64 * K + k0, Bl + i * 2048);
        __syncthreads();

        bf16x8 af[FM], bfv[FN];
#pragma unroll
        for (int i = 0; i < FM; ++i) af[i] = *(const bf16x8*)(Afr + i * 512);
#pragma unroll
        for (int j = 0; j < FN; ++j) bfv[j] = *(const bf16x8*)(Bfr + j * 512);
#pragma unroll
        for (int i = 0; i < FM; ++i)
#pragma unroll
            for (int j = 0; j < FN; ++j)
                acc[i][j] = __builtin_amdgcn_mfma_f32_16x16x32_bf16(
                    af[i], bfv[j], acc[i][j], 0, 0, 0);
    }

    const int crow0 = m0 + wr * FM * 16 + ((lane >> 4) << 2);
    const int ccol0 = n0 + wc * FN * 16 + (lane & 15);
#pragma unroll
    for (int i = 0; i < FM; ++i)
#pragma unroll
        for (int j = 0; j < FN; ++j)
#pragma unroll
            for (int r = 0; r < 4; ++r) {
                const size_t off = (size_t)(crow0 + i * 16 + r) * N + ccol0 + j * 16;
                float v = acc[i][j][r];
                if (EPI == 1) {
                    const float gg = bf2f(((const ushort_t*)extra)[off]);
                    v *= gg / (1.f + __expf(-gg));
                    ((ushort_t*)Cout)[off] = f2bf_rne(v);
                } else if (EPI == 2) {
                    ((float*)Cout)[off] = v + ((const float*)extra)[off];
                } else if (EPI == 3) {
                    ((ushort_t*)Cout)[off] = f2bf_rne(v);
                } else {
                    ((float*)Cout)[off] = v;
                }
            }
}

// ---------------- act[i] = silu(g[i]) * u[i], in-place on u -----------------
__global__ __launch_bounds__(256) void silu_mul_inplace(const ushort_t* __restrict__ g,
                                                        ushort_t* __restrict__ u) {
    const int i = blockIdx.x * 256 + threadIdx.x;   // chunk of 8 bf16
    const uint4 gv = ((const uint4*)g)[i];
    const uint4 uv = ((const uint4*)u)[i];
    const unsigned gw[4] = {gv.x, gv.y, gv.z, gv.w};
    const unsigned uw[4] = {uv.x, uv.y, uv.z, uv.w};
    unsigned ow[4];
#pragma unroll
    for (int j = 0; j < 4; ++j) {
        const float g0 = bf2f((ushort_t)(gw[j] & 0xffff));
        const float g1 = bf2f((ushort_t)(gw[j] >> 16));
        const float u0 = bf2f((ushort_t)(uw[j] & 0xffff));
        const float u1 = bf2f((ushort_t)(uw[j] >> 16));
        const float v0 = g0 / (1.f + __expf(-g0)) * u0;
        const float v1 = g1 / (1.f + __expf(-g1)) * u1;
        ow[j] = (unsigned)f2bf_rne(v0) | ((unsigned)f2bf_rne(v1) << 16);
    }
    ((uint4*)u)[i] = (uint4){ow[0], ow[1], ow[2], ow[3]};
}

// ---------------- topk body (device fn, shared by both launch forms) --------
__device__ __forceinline__ void topk_body(int t, const float* __restrict__ q,
                                          const float* __restrict__ keys,
                                          int* __restrict__ eidx,
                                          float* __restrict__ ewgt) {
    const int head = threadIdx.x >> 6;
    const int lane = threadIdx.x & 63;

    const float4* qx = (const float4*)&q[(size_t)t * 256 + head * 32];
    const float4* qy = (const float4*)&q[(size_t)t * 256 + 128 + head * 32];
    float4 qxv[8], qyv[8];
#pragma unroll
    for (int n = 0; n < 8; ++n) { qxv[n] = qx[n]; qyv[n] = qy[n]; }

    float cx0, cx1, cy0, cy1;
    {
        float s[4];
#pragma unroll
        for (int j = 0; j < 2; ++j) {
            const int k = 2 * lane + j;
            const float4* kx = (const float4*)&keys[(size_t)(((head << 7) | k) * 2 + 0) * 32];
            const float4* ky = (const float4*)&keys[(size_t)(((head << 7) | k) * 2 + 1) * 32];
            float sx = 0.f, sy = 0.f;
#pragma unroll
            for (int n = 0; n < 8; ++n) {
                const float4 a = qxv[n], b = kx[n];
                sx += a.x * b.x + a.y * b.y + a.z * b.z + a.w * b.w;
                const float4 c = qyv[n], d = ky[n];
                sy += c.x * d.x + c.y * d.y + c.z * d.z + c.w * d.w;
            }
            s[j * 2] = sx; s[j * 2 + 1] = sy;
        }
        cx0 = s[0]; cy0 = s[1]; cx1 = s[2]; cy1 = s[3];
    }

    float sx_mine = NINF, sy_mine = NINF;
    int sxi_mine = 0, syi_mine = 0;
    {
        float c0 = cx0, c1 = cx1;
#pragma unroll
        for (int it = 0; it < TOPK; ++it) {
            float bv; int bi;
            if (c1 > c0) { bv = c1; bi = 2 * lane + 1; } else { bv = c0; bi = 2 * lane; }
#pragma unroll
            for (int m = 1; m < 64; m <<= 1) {
                const float ov = __shfl_xor(bv, m);
                const int   oi = __shfl_xor(bi, m);
                if (ov > bv || (ov == bv && oi < bi)) { bv = ov; bi = oi; }
            }
            if (lane == it) { sx_mine = bv; sxi_mine = bi; }
            if (bi == 2 * lane) c0 = NINF;
            else if (bi == 2 * lane + 1) c1 = NINF;
        }
    }
    {
        float c0 = cy0, c1 = cy1;
#pragma unroll
        for (int it = 0; it < TOPK; ++it) {
            float bv; int bi;
            if (c1 > c0) { bv = c1; bi = 2 * lane + 1; } else { bv = c0; bi = 2 * lane; }
#pragma unroll
            for (int m = 1; m < 64; m <<= 1) {
                const float ov = __shfl_xor(bv, m);
                const int   oi = __shfl_xor(bi, m);
                if (ov > bv || (ov == bv && oi < bi)) { bv = ov; bi = oi; }
            }
            if (lane == it) { sy_mine = bv; syi_mine = bi; }
            if (bi == 2 * lane) c0 = NINF;
            else if (bi == 2 * lane + 1) c1 = NINF;
        }
    }

    const float sa = __shfl(sx_mine, lane >> 3);
    const int   ia = __shfl(sxi_mine, lane >> 3);
    const float sb = __shfl(sy_mine, lane & 7);
    const int   ib = __shfl(syi_mine, lane & 7);
    float cv = sa + sb;
    const int ci = ia * NKEYS + ib;

    float fs_mine = NINF; int fi_mine = 0;
#pragma unroll
    for (int it = 0; it < TOPK; ++it) {
        float bv = cv; int bp = lane; int bx = ci;
#pragma unroll
        for (int m = 1; m < 64; m <<= 1) {
            const float ov = __shfl_xor(bv, m);
            const int   op = __shfl_xor(bp, m);
            const int   ox = __shfl_xor(bx, m);
            if (ov > bv || (ov == bv && op < bp)) { bv = ov; bp = op; bx = ox; }
        }
        if (lane == it) { fs_mine = bv; fi_mine = bx; }
        if (lane == bp) cv = NINF;
    }

    float f[8];
#pragma unroll
    for (int j = 0; j < 8; ++j) f[j] = __shfl(fs_mine, j);
    float mx = f[0];
#pragma unroll
    for (int j = 1; j < 8; ++j) mx = fmaxf(mx, f[j]);
    float ssum = 0.f;
#pragma unroll
    for (int j = 0; j < 8; ++j) ssum += expf(f[j] - mx);
    if (lane < 8) {
        eidx[t * 32 + head * 8 + lane] = fi_mine;
        ewgt[t * 32 + head * 8 + lane] = expf(fs_mine - mx) / ssum;
    }
}

// ---------------- topk alone (R12 fallback) ---------------------------------
__global__ __launch_bounds__(256) void topk_kernel(const float* __restrict__ q,
                                                   const float* __restrict__ keys,
                                                   int* __restrict__ eidx,
                                                   float* __restrict__ ewgt) {
    topk_body(blockIdx.x, q, keys, eidx, ewgt);
}

// ---------------- topk + expert-table f32->bf16 conversion [NEW] ------------
// blocks [0,2048): topk; blocks [2048, 2048+16384): convert 2048 elems each
// (first 8192 -> deb, next 8192 -> ueb).
__global__ __launch_bounds__(256) void topk_conv_kernel(
    const float* __restrict__ q, const float* __restrict__ keys,
    int* __restrict__ eidx, float* __restrict__ ewgt,
    const float* __restrict__ de_f32, const float* __restrict__ ue_f32,
    ushort_t* __restrict__ deb, ushort_t* __restrict__ ueb) {
    const int b = blockIdx.x;
    if (b < TOKENS) {
        topk_body(b, q, keys, eidx, ewgt);
        return;
    }
    const int id = b - TOKENS;                       // 0..16383
    const float* src = (id < 8192) ? de_f32 : ue_f32;
    ushort_t*    dst = (id < 8192) ? deb : ueb;
    const size_t off = (size_t)(id & 8191) * 2048 + threadIdx.x * 8;
    const float4* p = (const float4*)(src + off);
    const float4 a = p[0], bb = p[1];
    uint4 o;
    o.x = (unsigned)f2bf_rne(a.x)  | ((unsigned)f2bf_rne(a.y)  << 16);
    o.y = (unsigned)f2bf_rne(a.z)  | ((unsigned)f2bf_rne(a.w)  << 16);
    o.z = (unsigned)f2bf_rne(bb.x) | ((unsigned)f2bf_rne(bb.y) << 16);
    o.w = (unsigned)f2bf_rne(bb.z) | ((unsigned)f2bf_rne(bb.w) << 16);
    *(uint4*)(dst + off) = o;
}

// ---------------- FUSED: gate GEMM + up GEMM + experts blocks ---------------
// BF16T=1: expert tables are bf16 (deb/ueb); 0: f32 (d_in). Same structure.
template<int BF16T>
__global__ __launch_bounds__(256) void fused3_kernel(
    const ushort_t* __restrict__ A,  const ushort_t* __restrict__ Bgate,
    const ushort_t* __restrict__ Bup, ushort_t* __restrict__ G,
    ushort_t* __restrict__ U,
    const float* __restrict__ hs, const void* __restrict__ de_tab,
    const void* __restrict__ ue_tab, const int* __restrict__ eidx,
    const float* __restrict__ ewgt, float* __restrict__ estate) {
    __shared__ __align__(16) char smem[16896];
    const int b = blockIdx.x;
    const int tid = threadIdx.x;
    const int w = tid >> 6, lane = tid & 63;
    const int r6 = b % 6;

    if (r6 == 2 || r6 == 5) {
        const ushort_t* B = (r6 == 2) ? Bgate : Bup;
        ushort_t*      C  = (r6 == 2) ? G : U;
        const int id = b / 6;
        const int m0 = (id >> 4) * 64, n0 = (id & 15) * 128;
        const int N = INTER, K = DIM;
        ushort_t* As = (ushort_t*)smem;             // 4 KB
        ushort_t* Bs = (ushort_t*)(smem + 4096);    // 8 KB
        const int wc = w;                            // WR=1 -> wr=0
        const int srow = (w << 4) + (lane >> 2);
        const int scol = (lane & 3) << 3;
        const ushort_t* Ag = &A[(size_t)(m0 + srow) * K + scol];
        const ushort_t* Bg = &B[(size_t)(n0 + srow) * K + scol];
        ushort_t* Al = &As[w << 9];
        ushort_t* Bl = &Bs[w << 9];
        const int frow = lane & 15;
        const int fcol = (lane >> 4) << 3;
        const ushort_t* Afr = &As[(size_t)frow * 32 + fcol];
        const ushort_t* Bfr = &Bs[(size_t)(wc * 32 + frow) * 32 + fcol];

        f32x4 acc[4][2];
#pragma unroll
        for (int i = 0; i < 4; ++i)
#pragma unroll
            for (int j = 0; j < 2; ++j) acc[i][j] = (f32x4){0.f, 0.f, 0.f, 0.f};

        for (int k0 = 0; k0 < K; k0 += 32) {
            __syncthreads();
            gload_lds16(Ag + k0, Al);
#pragma unroll
            for (int i = 0; i < 2; ++i)
                gload_lds16(Bg + (size_t)i * 64 * K + k0, Bl + i * 2048);
            __syncthreads();

            bf16x8 af[4], bfv[2];
#pragma unroll
            for (int i = 0; i < 4; ++i) af[i] = *(const bf16x8*)(Afr + i * 512);
#pragma unroll
            for (int j = 0; j < 2; ++j) bfv[j] = *(const bf16x8*)(Bfr + j * 512);
#pragma unroll
            for (int i = 0; i < 4; ++i)
#pragma unroll
                for (int j = 0; j < 2; ++j)
                    acc[i][j] = __builtin_amdgcn_mfma_f32_16x16x32_bf16(
                        af[i], bfv[j], acc[i][j], 0, 0, 0);
        }

        const int crow0 = m0 + ((lane >> 4) << 2);
        const int ccol0 = n0 + wc * 32 + (lane & 15);
#pragma unroll
        for (int i = 0; i < 4; ++i)
#pragma unroll
            for (int j = 0; j < 2; ++j)
#pragma unroll
                for (int r = 0; r < 4; ++r) {
                    const size_t off = (size_t)(crow0 + i * 16 + r) * N + ccol0 + j * 16;
                    C[off] = f2bf_rne(acc[i][j][r]);
                }
    } else {
        const int t = (b / 6) * 4 + r6 - (r6 > 2 ? 1 : 0);
        float4 (*partial)[256] = (float4(*)[256])smem;      // 16 KB
        int*   eid = (int*)(smem + 16384);                  // 128 B
        float* wl  = (float*)(smem + 16512);                // 128 B

        if (tid < 32) { eid[tid] = eidx[t * 32 + tid]; wl[tid] = ewgt[t * 32 + tid]; }

        const float4* hs4 = (const float4*)hs + (size_t)t * 256;
        float4 h[4];
#pragma unroll
        for (int i = 0; i < 4; ++i) h[i] = hs4[i * 64 + lane];
        __syncthreads();

        float4 acc[4];
#pragma unroll
        for (int i = 0; i < 4; ++i) acc[i] = (float4){0.f, 0.f, 0.f, 0.f};

        if (BF16T) {
            // bf16 tables: row = 1024 bf16 = 256 ushort4; chunk i at i*64+lane
            const ushort4* de4 = (const ushort4*)de_tab;
            const ushort4* ue4 = (const ushort4*)ue_tab;
            ushort4 d[4], u[4], nd[4], nu[4];
            {
                const size_t bb = (size_t)eid[w * 8] * 256;
#pragma unroll
                for (int i = 0; i < 4; ++i) { d[i] = de4[bb + i * 64 + lane]; u[i] = ue4[bb + i * 64 + lane]; }
            }
#pragma unroll
            for (int jj = 0; jj < 8; ++jj) {
                if (jj < 7) {
                    const size_t bb = (size_t)eid[w * 8 + jj + 1] * 256;
#pragma unroll
                    for (int i = 0; i < 4; ++i) { nd[i] = de4[bb + i * 64 + lane]; nu[i] = ue4[bb + i * 64 + lane]; }
                }
                float s = 0.f;
#pragma unroll
                for (int i = 0; i < 4; ++i)
                    s += h[i].x * bf2f(d[i].x) + h[i].y * bf2f(d[i].y)
                       + h[i].z * bf2f(d[i].z) + h[i].w * bf2f(d[i].w);
#pragma unroll
                for (int m = 1; m < 64; m <<= 1) s += __shfl_xor(s, m);
                const float c = (s / (1.f + __expf(-s))) * wl[w * 8 + jj];
#pragma unroll
                for (int i = 0; i < 4; ++i) {
                    acc[i].x += c * bf2f(u[i].x); acc[i].y += c * bf2f(u[i].y);
                    acc[i].z += c * bf2f(u[i].z); acc[i].w += c * bf2f(u[i].w);
                }
                if (jj < 7) {
#pragma unroll
                    for (int i = 0; i < 4; ++i) { d[i] = nd[i]; u[i] = nu[i]; }
                }
            }
        } else {
            const float4* de4 = (const float4*)de_tab;
            const float4* ue4 = (const float4*)ue_tab;
            float4 d[4], u[4], nd[4], nu[4];
            {
                const size_t bb = (size_t)eid[w * 8] * 256;
#pragma unroll
                for (int i = 0; i < 4; ++i) { d[i] = de4[bb + i * 64 + lane]; u[i] = ue4[bb + i * 64 + lane]; }
            }
#pragma unroll
            for (int jj = 0; jj < 8; ++jj) {
                if (jj < 7) {
                    const size_t bb = (size_t)eid[w * 8 + jj + 1] * 256;
#pragma unroll
                    for (int i = 0; i < 4; ++i) { nd[i] = de4[bb + i * 64 + lane]; nu[i] = ue4[bb + i * 64 + lane]; }
                }
                float s = 0.f;
#pragma unroll
                for (int i = 0; i < 4; ++i)
                    s += h[i].x * d[i].x + h[i].y * d[i].y + h[i].z * d[i].z + h[i].w * d[i].w;
#pragma unroll
                for (int m = 1; m < 64; m <<= 1) s += __shfl_xor(s, m);
                const float c = (s / (1.f + __expf(-s))) * wl[w * 8 + jj];
#pragma unroll
                for (int i = 0; i < 4; ++i) {
                    acc[i].x += c * u[i].x; acc[i].y += c * u[i].y;
                    acc[i].z += c * u[i].z; acc[i].w += c * u[i].w;
                }
                if (jj < 7) {
#pragma unroll
                    for (int i = 0; i < 4; ++i) { d[i] = nd[i]; u[i] = nu[i]; }
                }
            }
        }

#pragma unroll
        for (int i = 0; i < 4; ++i) partial[w][i * 64 + lane] = acc[i];
        __syncthreads();

        const float4 p0 = partial[0][tid], p1 = partial[1][tid];
        const float4 p2 = partial[2][tid], p3 = partial[3][tid];
        float4 o;
        o.x = p0.x + p1.x + p2.x + p3.x;
        o.y = p0.y + p1.y + p2.y + p3.y;
        o.z = p0.z + p1.z + p2.z + p3.z;
        o.w = p0.w + p1.w + p2.w + p3.w;
        ((float4*)estate)[(size_t)t * 256 + tid] = o;
    }
}

// ---------------------------------------------------------------------------
extern "C" void kernel_launch(void* const* d_in, const int* in_sizes, int n_in,
                              void* d_out, int out_size, void* d_ws, size_t ws_size,
                              hipStream_t stream) {
    (void)in_sizes; (void)n_in; (void)out_size;
    const float* hidden = (const float*)d_in[0];
    const float* wq     = (const float*)d_in[1];
    const float* keys   = (const float*)d_in[2];
    const float* down_e = (const float*)d_in[3];
    const float* up_e   = (const float*)d_in[4];
    const float* wgate  = (const float*)d_in[5];
    const float* wup    = (const float*)d_in[6];
    const float* wdown  = (const float*)d_in[7];
    float* out = (float*)d_out;
    char* ws = (char*)d_ws;

    // workspace layout: EXACT round-12 (passed) + optional bf16 tables after.
    ushort_t* hb  = (ushort_t*)(ws);                     // 4 MB
    ushort_t* wqb = (ushort_t*)(ws + (4u << 20));        // 0.5 MB
    ushort_t* wgb = (ushort_t*)(ws + (4608u << 10));     // 4 MB
    ushort_t* wub = (ushort_t*)(ws + (8704u << 10));     // 4 MB
    ushort_t* wdb = (ushort_t*)(ws + (12800u << 10));    // 4 MB
    float*    q   = (float*)   (ws + (16896u << 10));    // 2 MB
    ushort_t* act = (ushort_t*)(ws + (18944u << 10));    // 8 MB (raw u, then act)
    ushort_t* g   = (ushort_t*)(ws + (27136u << 10));    // 8 MB
    float*    wgt = (float*)   (ws + (35328u << 10));    // 0.25 MB
    int*     eidx = (int*)     (ws + (35584u << 10));    // 0.25 MB  (end 35.84 MB)
    ushort_t* deb = (ushort_t*)(ws + 36700160u);         // 32 MB
    ushort_t* ueb = (ushort_t*)(ws + 70254592u);         // 32 MB (end 103809024)
    float* estate = out;                                 // 8 MB, in d_out

    const bool bf16t = ws_size >= 103809024ull;          // host-side, deterministic

    convert_all<<<4224, 256, 0, stream>>>(hidden, wq, wgate, wup, wdown,
                                          hb, wqb, wgb, wub, wdb);

    // 1) q = hidden @ wq^T  (2048 x 256 x 1024), f32 out for routing
    mfma_gemm<64, 64, 2, 2, 2, 2, 0><<<dim3(4, 32), 256, 0, stream>>>(
        hb, wqb, nullptr, q, TOKENS, 256, DIM);

    if (bf16t) {
        // 2) routing + expert-table bf16 conversion (independent blocks)
        topk_conv_kernel<<<TOKENS + 16384, 256, 0, stream>>>(
            q, keys, eidx, wgt, down_e, up_e, deb, ueb);
        // 3+4+5 FUSED) g/u GEMMs || experts (bf16 tables) -> out
        fused3_kernel<1><<<3072, 256, 0, stream>>>(
            hb, wgb, wub, g, act, hidden, deb, ueb, eidx, wgt, estate);
    } else {
        // fallback: exact R12 path
        topk_kernel<<<TOKENS, 256, 0, stream>>>(q, keys, eidx, wgt);
        fused3_kernel<0><<<3072, 256, 0, stream>>>(
            hb, wgb, wub, g, act, hidden, down_e, up_e, eidx, wgt, estate);
    }

    // 4b) act = silu(g) * u, in-place on the u buffer
    silu_mul_inplace<<<2048, 256, 0, stream>>>(g, act);
    // 6) out = act @ wdown^T + out(=estate)
    mfma_gemm<64, 64, 2, 2, 2, 2, 2><<<dim3(16, 32), 256, 0, stream>>>(
        act, wdb, estate, out, TOKENS, DIM, INTER);
}